// Round 6
// baseline (717.130 us; speedup 1.0000x reference)
//
#include <hip/hip_runtime.h>
#include <math.h>

// FAVOR+ (Performer) non-causal linear attention, b=4 h=8 n=8192 d=64 f=266.
// Round 6: p1 = round-2 kernel + V-load hoist (latency hidden under phi MFMAs).
// p2 = barrier-free redesign: wave owns 16 rows end-to-end, wave-private LDS
// qp staging, ctx hi/lo read from L2, 37KB LDS -> multi-block residency.
// No occupancy attributes (rounds 3/5 showed they trigger 64-VGPR spill storms).

typedef __attribute__((ext_vector_type(8))) short s16x8;
typedef __attribute__((ext_vector_type(4))) float f32x4;

#define MFMA16(a,b,c) __builtin_amdgcn_mfma_f32_16x16x32_bf16((a),(b),(c),0,0,0)

__device__ __forceinline__ unsigned short bf16rne(float x){
  unsigned u = __float_as_uint(x);
  u = u + 0x7fffu + ((u >> 16) & 1u);
  return (unsigned short)(u >> 16);
}
__device__ __forceinline__ float bf16tof(unsigned short h){
  return __uint_as_float(((unsigned)h) << 16);
}
__device__ __forceinline__ void cvt_hl8(const float v[8], s16x8& h, s16x8& l){
  #pragma unroll
  for(int j=0;j<8;++j){
    unsigned short hh = bf16rne(v[j]);
    h[j] = (short)hh;
    l[j] = (short)bf16rne(v[j] - bf16tof(hh));
  }
}

// ---------------- prep: scaled/padded proj hi/lo ----------------
__global__ void fa21_prep(const float* __restrict__ proj, short* __restrict__ ph,
                          short* __restrict__ pl, float pscale){
  int idx = blockIdx.x*256 + threadIdx.x;
  if(idx >= 288*64) return;
  int f = idx >> 6, dc = idx & 63;
  float v = (f < 266) ? proj[f*64 + dc]*pscale : 0.f;
  unsigned short hh = bf16rne(v);
  ph[idx] = (short)hh;
  pl[idx] = (short)bf16rne(v - bf16tof(hh));
}

// ---------------- phase 1: kp -> context partials + ksum partials ----------------
// grid 256 = 32 heads x 8 chunks, 512 threads (8 waves), 8 iters of 128 rows.
// LDS: proj h/l [288][64] swz(f&7), kp hi f-major [288][128] swz(f&15), sks [8][288].
__global__ __launch_bounds__(512,2) void fa21_p1(
    const float* __restrict__ kin, const float* __restrict__ vin,
    const short* __restrict__ pjh, const short* __restrict__ pjl,
    float* __restrict__ ctx_part, float* __restrict__ ksum_part,
    float koff, float diagc){
  extern __shared__ char smem[];
  char* sph = smem;
  char* spl = smem + 36864;
  char* skh = smem + 73728;
  float* sks = (float*)(smem + 147456);
  const int tid = threadIdx.x;
  const int w = tid >> 6, lane = tid & 63, g = lane >> 4, q = lane & 15;
  const int bid = blockIdx.x;
  const int head = bid & 31, chunk = bid >> 5;
  for(int i = tid; i < 288*64; i += 512){
    int f = i >> 6, dc = i & 63;
    int byt = (f*128 + dc*2) ^ ((f & 7) << 4);
    *(short*)(sph + byt) = pjh[i];
    *(short*)(spl + byt) = pjl[i];
  }
  __syncthreads();
  const int eH = w >> 1, fHc = w & 1;   // ctx role: 2 f-halves x 4 e-tiles
  f32x4 acc[9];
  #pragma unroll
  for(int a=0;a<9;++a){ f32x4 z = {0.f,0.f,0.f,0.f}; acc[a] = z; }
  float ksacc[18];
  #pragma unroll
  for(int a=0;a<18;++a) ksacc[a] = 0.f;
  const float* kbase = kin + (size_t)head*8192*64;
  const float* vbase = vin + (size_t)head*8192*64;
  #pragma unroll 1
  for(int it = 0; it < 8; ++it){
    const int nb = chunk*1024 + it*128;
    // ---- X A-frags: wave rows w*16..+16, lane row = q, k=d contiguous
    s16x8 xh[2], xl[2];
    float diag;
    {
      const float* rp = kbase + (size_t)(nb + w*16 + q)*64;
      float ss = 0.f;
      #pragma unroll
      for(int ks=0; ks<2; ++ks){
        float4 a = *(const float4*)(rp + ks*32 + g*8);
        float4 b = *(const float4*)(rp + ks*32 + g*8 + 4);
        float vv[8] = {a.x,a.y,a.z,a.w,b.x,b.y,b.z,b.w};
        #pragma unroll
        for(int j=0;j<8;++j) ss += vv[j]*vv[j];
        cvt_hl8(vv, xh[ks], xl[ks]);
      }
      ss += __shfl_xor(ss, 16); ss += __shfl_xor(ss, 32);
      diag = ss * diagc;
    }
    float dro[4];
    #pragma unroll
    for(int i=0;i<4;++i) dro[i] = __shfl(diag, 4*g + i) - koff;
    // ---- V B-frags HOISTED: issue global loads now, latency hides under phi
    s16x8 vh[4], vl[4];
    {
      const int e = eH*16 + q;
      #pragma unroll
      for(int ks=0; ks<4; ++ks){
        float vv[8];
        #pragma unroll
        for(int i2=0;i2<8;++i2) vv[i2] = vbase[(size_t)(nb + ks*32 + 8*g + i2)*64 + e];
        cvt_hl8(vv, vh[ks], vl[ks]);
      }
    }
    // ---- phi: S = X * projT (3-product), all 18 f-tiles
    f32x4 S[18];
    #pragma unroll
    for(int ftl=0;ftl<18;++ftl){ f32x4 z = {0.f,0.f,0.f,0.f}; S[ftl] = z; }
    #pragma unroll
    for(int ftl=0; ftl<18; ++ftl){
      const int f = ftl*16 + q;
      #pragma unroll
      for(int ks=0; ks<2; ++ks){
        int byt = (f*128 + ks*64 + g*16) ^ ((f & 7) << 4);
        s16x8 bph = *(const s16x8*)(sph + byt);
        s16x8 bpl = *(const s16x8*)(spl + byt);
        S[ftl] = MFMA16(xh[ks], bph, S[ftl]);
        S[ftl] = MFMA16(xl[ks], bph, S[ftl]);
        S[ftl] = MFMA16(xh[ks], bpl, S[ftl]);
      }
    }
    // ---- kp = exp2(S - diag + koff), mask, ksum, pack hi -> LDS f-major swz
    #pragma unroll
    for(int ftl=0; ftl<18; ++ftl){
      const int f = ftl*16 + q;
      const bool live = (f < 266);
      float p[4];
      #pragma unroll
      for(int i=0;i<4;++i){
        float e = exp2f(S[ftl][i] - dro[i]);
        p[i] = live ? e : 0.f;
      }
      ksacc[ftl] += p[0]+p[1]+p[2]+p[3];
      uint2 hv;
      hv.x = (unsigned)bf16rne(p[0]) | ((unsigned)bf16rne(p[1]) << 16);
      hv.y = (unsigned)bf16rne(p[2]) | ((unsigned)bf16rne(p[3]) << 16);
      int byt = (f*256 + (w*16 + 4*g)*2) ^ ((f & 15) << 4);
      *(uint2*)(skh + byt) = hv;
    }
    __syncthreads();   // kp ready
    // ---- context += kpT * V (2-product: kh*vh + kh*vl)
    #pragma unroll
    for(int fm=0; fm<9; ++fm){
      const int fg = (fHc*9 + fm)*16 + q;
      #pragma unroll
      for(int ks=0; ks<4; ++ks){
        int byt = (fg*256 + ks*64 + 16*g) ^ ((fg & 15) << 4);
        s16x8 kh = *(const s16x8*)(skh + byt);
        acc[fm] = MFMA16(kh, vh[ks], acc[fm]);
        acc[fm] = MFMA16(kh, vl[ks], acc[fm]);
      }
    }
    __syncthreads();   // kp LDS reusable
  }
  // ---- store context partials
  float* cp = ctx_part + (size_t)bid*288*64;
  #pragma unroll
  for(int fm=0; fm<9; ++fm){
    #pragma unroll
    for(int i=0;i<4;++i){
      int f = (fHc*9 + fm)*16 + 4*g + i;
      int e = eH*16 + q;
      cp[f*64 + e] = acc[fm][i];
    }
  }
  // ---- ksum partials: reduce over g, one writer per (w,f)
  #pragma unroll
  for(int ftl=0; ftl<18; ++ftl){
    float s = ksacc[ftl];
    s += __shfl_xor(s, 16); s += __shfl_xor(s, 32);
    if(g == 0) sks[w*288 + ftl*16 + q] = s;
  }
  __syncthreads();
  for(int i = tid; i < 288; i += 512){
    float s = 0.f;
    #pragma unroll
    for(int ww=0; ww<8; ++ww) s += sks[ww*288 + i];
    ksum_part[(size_t)bid*288 + i] = s;
  }
}

// ---------------- reduce: sum 8 chunk partials -> cT hi/lo (e-major) + ksum ----------------
__global__ void fa21_reduce(const float* __restrict__ ctx_part, const float* __restrict__ ksum_part,
                            short* __restrict__ cth, short* __restrict__ ctl, float* __restrict__ ksum){
  int h = blockIdx.x, tid = threadIdx.x;
  for(int idx = tid; idx < 288*64; idx += 256){
    float s = 0.f;
    #pragma unroll
    for(int c=0;c<8;++c) s += ctx_part[(size_t)(h + 32*c)*288*64 + idx];
    int f = idx >> 6, e = idx & 63;
    unsigned short hh = bf16rne(s);
    cth[(size_t)h*64*288 + e*288 + f] = (short)hh;
    ctl[(size_t)h*64*288 + e*288 + f] = (short)bf16rne(s - bf16tof(hh));
  }
  for(int idx = tid; idx < 288; idx += 256){
    float s = 0.f;
    #pragma unroll
    for(int c=0;c<8;++c) s += ksum_part[(size_t)(h + 32*c)*288 + idx];
    ksum[h*288 + idx] = s;
  }
}

// ---------------- phase 2: qp -> out (BARRIER-FREE) ----------------
// grid 1024 = 32 heads x 32 chunks, 256 threads (4 waves), 4 iters of 64 rows.
// Each wave owns 16 rows end-to-end: phi (18 f-tiles), wave-local rowmax/denom,
// qp staged in WAVE-PRIVATE LDS (16 rows x 296 shorts = 9472 B), out-GEMM with
// ctx hi/lo B-frags from global (L2-resident, shared across the 4 waves).
// LDS total: 4 x 9472 = 37888. No __syncthreads anywhere in the loop.
__global__ __launch_bounds__(256) void fa21_p2(
    const float* __restrict__ qin,
    const short* __restrict__ pjh, const short* __restrict__ pjl,
    const short* __restrict__ cth, const short* __restrict__ ctl,
    const float* __restrict__ ksum, float* __restrict__ outp,
    float qoff, float qeps, float diagc){
  extern __shared__ char smem[];
  const int tid = threadIdx.x;
  const int w = tid >> 6, lane = tid & 63, g = lane >> 4, q = lane & 15;
  char* sq = smem + w*9472;                 // wave-private qp staging
  const int bid = blockIdx.x;
  const int head = bid & 31, chunk = bid >> 5;
  float ksv[18];
  #pragma unroll
  for(int ftl=0; ftl<18; ++ftl) ksv[ftl] = ksum[head*288 + ftl*16 + q];
  const float* qbase = qin + (size_t)head*8192*64;
  float* obase = outp + (size_t)head*8192*64;
  const short* cbh = cth + (size_t)head*18432;
  const short* cbl = ctl + (size_t)head*18432;
  #pragma unroll 1
  for(int it=0; it<4; ++it){
    const int row0 = chunk*256 + it*64 + w*16;
    // ---- X A-frags: lane row = q
    s16x8 xh[2], xl[2];
    float diag;
    {
      const float* rp = qbase + (size_t)(row0 + q)*64;
      float ss = 0.f;
      #pragma unroll
      for(int ks=0; ks<2; ++ks){
        float4 a = *(const float4*)(rp + ks*32 + g*8);
        float4 b = *(const float4*)(rp + ks*32 + g*8 + 4);
        float vv[8] = {a.x,a.y,a.z,a.w,b.x,b.y,b.z,b.w};
        #pragma unroll
        for(int j=0;j<8;++j) ss += vv[j]*vv[j];
        cvt_hl8(vv, xh[ks], xl[ks]);
      }
      ss += __shfl_xor(ss, 16); ss += __shfl_xor(ss, 32);
      diag = ss * diagc;
    }
    // ---- phi: all 18 f-tiles (3-product), proj from global (L2)
    f32x4 S[18];
    #pragma unroll
    for(int ftl=0;ftl<18;++ftl){ f32x4 z = {0.f,0.f,0.f,0.f}; S[ftl] = z; }
    #pragma unroll
    for(int ftl=0; ftl<18; ++ftl){
      const int f = ftl*16 + q;
      #pragma unroll
      for(int ks=0; ks<2; ++ks){
        s16x8 bph = *(const s16x8*)(pjh + f*64 + ks*32 + g*8);
        s16x8 bpl = *(const s16x8*)(pjl + f*64 + ks*32 + g*8);
        S[ftl] = MFMA16(xh[ks], bph, S[ftl]);
        S[ftl] = MFMA16(xl[ks], bph, S[ftl]);
        S[ftl] = MFMA16(xh[ks], bpl, S[ftl]);
      }
    }
    // ---- rowmax: fully wave-local (lane reduce over ftl, shfl over q lanes)
    float dro[4];
    #pragma unroll
    for(int i=0;i<4;++i){
      float m = -3e38f;
      #pragma unroll
      for(int ftl=0; ftl<18; ++ftl){
        const int f = ftl*16 + q;
        float v = (f < 266) ? S[ftl][i] : -3e38f;
        m = fmaxf(m, v);
      }
      m = fmaxf(m, __shfl_xor(m, 1));
      m = fmaxf(m, __shfl_xor(m, 2));
      m = fmaxf(m, __shfl_xor(m, 4));
      m = fmaxf(m, __shfl_xor(m, 8));
      dro[i] = __shfl(diag, 4*g + i) + m - qoff;
    }
    // ---- qp = exp2(S - dro) + qeps, denom partial, hi -> wave-private LDS n-major
    float dnp[4] = {0.f,0.f,0.f,0.f};
    #pragma unroll
    for(int ftl=0; ftl<18; ++ftl){
      const int f = ftl*16 + q;
      const bool live = (f < 266);
      #pragma unroll
      for(int i=0;i<4;++i){
        float e = exp2f(S[ftl][i] - dro[i]) + qeps;
        float p = live ? e : 0.f;
        dnp[i] += p * ksv[ftl];
        *(short*)(sq + (4*g + i)*592 + f*2) = (short)bf16rne(p);
      }
    }
    float dinv[4];
    #pragma unroll
    for(int i=0;i<4;++i){
      float s = dnp[i];
      s += __shfl_xor(s, 1); s += __shfl_xor(s, 2);
      s += __shfl_xor(s, 4); s += __shfl_xor(s, 8);
      dinv[i] = 1.0f / (s + 1e-8f);
    }
    // ---- out GEMM: own 16 rows x all 64 e, K=288 (9 K-tiles), 2-product.
    // A from own LDS region (same-wave write->read, no barrier needed);
    // B = ctx hi/lo from global (L2, shared across waves).
    f32x4 oacc[4];
    #pragma unroll
    for(int et=0; et<4; ++et){ f32x4 z = {0.f,0.f,0.f,0.f}; oacc[et] = z; }
    #pragma unroll
    for(int ks=0; ks<9; ++ks){
      s16x8 ah = *(const s16x8*)(sq + q*592 + ks*64 + 16*g);
      #pragma unroll
      for(int et=0; et<4; ++et){
        const int e = et*16 + q;
        s16x8 ch = *(const s16x8*)(cbh + (size_t)e*288 + ks*32 + 8*g);
        s16x8 cl = *(const s16x8*)(cbl + (size_t)e*288 + ks*32 + 8*g);
        oacc[et] = MFMA16(ah, ch, oacc[et]);
        oacc[et] = MFMA16(ah, cl, oacc[et]);
      }
    }
    #pragma unroll
    for(int et=0; et<4; ++et){
      #pragma unroll
      for(int i=0;i<4;++i){
        obase[(size_t)(row0 + 4*g + i)*64 + et*16 + q] = oacc[et][i] * dinv[i];
      }
    }
  }
}

extern "C" void kernel_launch(void* const* d_in, const int* in_sizes, int n_in,
                              void* d_out, int out_size, void* d_ws, size_t ws_size,
                              hipStream_t stream){
  const float* q    = (const float*)d_in[0];
  const float* k    = (const float*)d_in[1];
  const float* v    = (const float*)d_in[2];
  const float* proj = (const float*)d_in[3];
  float* out = (float*)d_out;
  char* ws = (char*)d_ws;
  short* wproj_h = (short*)(ws);
  short* wproj_l = (short*)(ws + 36864);
  float* wctx    = (float*)(ws + 73728);
  float* wksump  = (float*)(ws + 18948096);          // 73728 + 256*73728
  short* wct_h   = (short*)(ws + 19243008);          // + 256*288*4
  short* wct_l   = (short*)(ws + 20422656);          // + 32*64*288*2
  float* wksum   = (float*)(ws + 21602304);          // + 32*64*288*2

  const double LOG2E = 1.4426950408889634;
  const double ln_ratio = -0.5*log(266.0);
  float pscale = (float)(pow(64.0, -0.25) * LOG2E);
  float diagc  = (float)(0.0625 * LOG2E);
  float koff   = (float)((1e-4 + ln_ratio) * LOG2E);
  float qoff   = (float)(ln_ratio * LOG2E);
  float qeps   = (float)(1e-4 / sqrt(266.0));

  hipFuncSetAttribute((const void*)fa21_p1, hipFuncAttributeMaxDynamicSharedMemorySize, 156672);
  hipFuncSetAttribute((const void*)fa21_p2, hipFuncAttributeMaxDynamicSharedMemorySize, 37888);

  fa21_prep<<<72, 256, 0, stream>>>(proj, wproj_h, wproj_l, pscale);
  fa21_p1<<<256, 512, 156672, stream>>>(k, v, wproj_h, wproj_l, wctx, wksump, koff, diagc);
  fa21_reduce<<<32, 256, 0, stream>>>(wctx, wksump, wct_h, wct_l, wksum);
  fa21_p2<<<1024, 256, 37888, stream>>>(q, wproj_h, wproj_l, wct_h, wct_l, wksum, out,
                                        qoff, qeps, diagc);
}

// Round 7
// 383.133 us; speedup vs baseline: 1.8718x; 1.8718x over previous
//
#include <hip/hip_runtime.h>
#include <math.h>

// FAVOR+ (Performer) non-causal linear attention, b=4 h=8 n=8192 d=64 f=266.
// Round 7: p1 = 1024-thr, 4-way f-quarter split (S[5]/acc[5], VGPR~117 by design),
// f padded to 320 for uniform static tiling, proj hi/lo + kp in LDS, X prefetch.
// p2 = swapped-operand phi (S^T[f][n], n lane-local): barrier-free loop, qp
// assembled into MFMA frags via shuffles (no LDS round-trip), phi recomputed
// (pass1 rowmax / pass2 exp) to keep VGPR ~100; projH+ctxH+ksum in LDS (74KB)
// -> 2 blocks/CU = 4 waves/SIMD.

typedef __attribute__((ext_vector_type(8))) short s16x8;
typedef __attribute__((ext_vector_type(4))) float f32x4;

#define MFMA16(a,b,c) __builtin_amdgcn_mfma_f32_16x16x32_bf16((a),(b),(c),0,0,0)

__device__ __forceinline__ unsigned short bf16rne(float x){
  unsigned u = __float_as_uint(x);
  u = u + 0x7fffu + ((u >> 16) & 1u);
  return (unsigned short)(u >> 16);
}
__device__ __forceinline__ float bf16tof(unsigned short h){
  return __uint_as_float(((unsigned)h) << 16);
}
__device__ __forceinline__ void cvt_hl8(const float v[8], s16x8& h, s16x8& l){
  #pragma unroll
  for(int j=0;j<8;++j){
    unsigned short hh = bf16rne(v[j]);
    h[j] = (short)hh;
    l[j] = (short)bf16rne(v[j] - bf16tof(hh));
  }
}

// ---------------- prep: scaled/padded proj hi/lo (288 rows) ----------------
__global__ void fa21_prep(const float* __restrict__ proj, short* __restrict__ ph,
                          short* __restrict__ pl, float pscale){
  int idx = blockIdx.x*256 + threadIdx.x;
  if(idx >= 288*64) return;
  int f = idx >> 6, dc = idx & 63;
  float v = (f < 266) ? proj[f*64 + dc]*pscale : 0.f;
  unsigned short hh = bf16rne(v);
  ph[idx] = (short)hh;
  pl[idx] = (short)bf16rne(v - bf16tof(hh));
}

// ---------------- phase 1: kp -> context partials + ksum partials ----------------
// grid 256 = 32 heads x 8 chunks, 1024 thr (16 waves), 16 iters x 64 rows.
// phi role: (mtp = w&3 row-tile, fqp = w>>2 f-quarter of 5 tiles). 3-product phi.
// ctx role: (et = w&3, fqc = w>>2). K=64 per iter (2 k-slices), 2-product.
// LDS: projH [320][64] swz 40960 + projL 40960 + kp [320][64] swz 40960 = 122880.
__global__ __launch_bounds__(1024,1) void fa21_p1(
    const float* __restrict__ kin, const float* __restrict__ vin,
    const short* __restrict__ pjh, const short* __restrict__ pjl,
    float* __restrict__ ctx_part, float* __restrict__ ksum_part,
    float koff, float diagc){
  extern __shared__ char smem[];
  char* sph = smem;                     // 40960
  char* spl = smem + 40960;             // 40960
  char* skh = smem + 81920;             // 40960 (kp), overlaid by ex[] at end
  float* ex = (float*)(smem + 81920);
  const int tid = threadIdx.x;
  const int w = tid >> 6, lane = tid & 63, g = lane >> 4, q = lane & 15;
  const int bid = blockIdx.x;
  const int head = bid & 31, chunk = bid >> 5;
  // stage proj (320-pad, zero-fill beyond 288)
  for(int i = tid; i < 2560; i += 1024){
    int f = i >> 3;
    int byt = (f*128 + (i & 7)*16) ^ ((f & 7) << 4);
    s16x8 vh8 = {0,0,0,0,0,0,0,0}, vl8 = {0,0,0,0,0,0,0,0};
    if(f < 288){
      vh8 = ((const s16x8*)pjh)[i];
      vl8 = ((const s16x8*)pjl)[i];
    }
    *(s16x8*)(sph + byt) = vh8;
    *(s16x8*)(spl + byt) = vl8;
  }
  const int mtp = w & 3, fqp = w >> 2;
  const int et  = w & 3, fqc = w >> 2;
  f32x4 acc[5];
  #pragma unroll
  for(int a=0;a<5;++a){ f32x4 z = {0.f,0.f,0.f,0.f}; acc[a] = z; }
  float ksacc[5] = {0.f,0.f,0.f,0.f,0.f};
  const float* kbase = kin + (size_t)head*8192*64;
  const float* vbase = vin + (size_t)head*8192*64;
  // prefetch X for it=0
  float4 xa0, xb0, xa1, xb1;
  {
    const float* rp = kbase + (size_t)(chunk*1024 + mtp*16 + q)*64;
    xa0 = *(const float4*)(rp + g*8);       xb0 = *(const float4*)(rp + g*8 + 4);
    xa1 = *(const float4*)(rp + 32 + g*8);  xb1 = *(const float4*)(rp + 32 + g*8 + 4);
  }
  __syncthreads();
  #pragma unroll 1
  for(int it = 0; it < 16; ++it){
    const int nb = chunk*1024 + it*64;
    // ---- cvt prefetched X + diag
    s16x8 xh[2], xl[2];
    float diag;
    {
      float v0[8] = {xa0.x,xa0.y,xa0.z,xa0.w,xb0.x,xb0.y,xb0.z,xb0.w};
      float v1[8] = {xa1.x,xa1.y,xa1.z,xa1.w,xb1.x,xb1.y,xb1.z,xb1.w};
      float ss = 0.f;
      #pragma unroll
      for(int j=0;j<8;++j){ ss += v0[j]*v0[j]; ss += v1[j]*v1[j]; }
      cvt_hl8(v0, xh[0], xl[0]);
      cvt_hl8(v1, xh[1], xl[1]);
      ss += __shfl_xor(ss, 16); ss += __shfl_xor(ss, 32);
      diag = ss * diagc;
    }
    float dro[4];
    #pragma unroll
    for(int i=0;i<4;++i) dro[i] = __shfl(diag, 4*g + i) - koff;
    // ---- V loads (ctx role), issued before phi so latency hides under MFMAs
    s16x8 vh[2], vl[2];
    {
      const int e = et*16 + q;
      #pragma unroll
      for(int ks=0; ks<2; ++ks){
        float vv[8];
        #pragma unroll
        for(int i2=0;i2<8;++i2) vv[i2] = vbase[(size_t)(nb + ks*32 + 8*g + i2)*64 + e];
        cvt_hl8(vv, vh[ks], vl[ks]);
      }
    }
    // ---- phi: this wave's 5 f-tiles (3-product)
    f32x4 S[5];
    #pragma unroll
    for(int t=0;t<5;++t){ f32x4 z = {0.f,0.f,0.f,0.f}; S[t] = z; }
    #pragma unroll
    for(int t=0; t<5; ++t){
      const int f = (fqp*5 + t)*16 + q;
      #pragma unroll
      for(int ks=0; ks<2; ++ks){
        int byt = (f*128 + ks*64 + g*16) ^ ((f & 7) << 4);
        s16x8 bph = *(const s16x8*)(sph + byt);
        s16x8 bpl = *(const s16x8*)(spl + byt);
        S[t] = MFMA16(xh[ks], bph, S[t]);
        S[t] = MFMA16(xl[ks], bph, S[t]);
        S[t] = MFMA16(xh[ks], bpl, S[t]);
      }
    }
    // ---- kp = exp2(S - diag + koff), mask f>=266, ksum, hi -> kp LDS
    #pragma unroll
    for(int t=0; t<5; ++t){
      const int f = (fqp*5 + t)*16 + q;
      const bool live = (f < 266);
      float p[4];
      #pragma unroll
      for(int i=0;i<4;++i){
        float e2 = exp2f(S[t][i] - dro[i]);
        p[i] = live ? e2 : 0.f;
      }
      ksacc[t] += p[0]+p[1]+p[2]+p[3];
      uint2 hv;
      hv.x = (unsigned)bf16rne(p[0]) | ((unsigned)bf16rne(p[1]) << 16);
      hv.y = (unsigned)bf16rne(p[2]) | ((unsigned)bf16rne(p[3]) << 16);
      int byt = (f*128 + (mtp*16 + 4*g)*2) ^ ((f & 7) << 4);
      *(uint2*)(skh + byt) = hv;
    }
    // ---- prefetch X for next iter
    {
      const int itn = (it + 1) & 15;
      const float* rp = kbase + (size_t)(chunk*1024 + itn*64 + mtp*16 + q)*64;
      xa0 = *(const float4*)(rp + g*8);       xb0 = *(const float4*)(rp + g*8 + 4);
      xa1 = *(const float4*)(rp + 32 + g*8);  xb1 = *(const float4*)(rp + 32 + g*8 + 4);
    }
    __syncthreads();   // kp ready
    // ---- context += kpT * V (2-product)
    #pragma unroll
    for(int fm=0; fm<5; ++fm){
      const int fg = (fqc*5 + fm)*16 + q;
      #pragma unroll
      for(int ks=0; ks<2; ++ks){
        int byt = (fg*128 + ks*64 + g*16) ^ ((fg & 7) << 4);
        s16x8 kf = *(const s16x8*)(skh + byt);
        acc[fm] = MFMA16(kf, vh[ks], acc[fm]);
        acc[fm] = MFMA16(kf, vl[ks], acc[fm]);
      }
    }
    __syncthreads();   // kp LDS reusable
  }
  // ---- store context partials (skip padded tiles >= 18)
  {
    float* cp = ctx_part + (size_t)bid*288*64;
    #pragma unroll
    for(int fm=0; fm<5; ++fm){
      const int gt = fqc*5 + fm;
      if(gt < 18){
        #pragma unroll
        for(int i=0;i<4;++i){
          int f = gt*16 + 4*g + i;
          cp[f*64 + et*16 + q] = acc[fm][i];
        }
      }
    }
  }
  // ---- ksum: g-reduce, exchange over the 4 row-tile waves via freed kp LDS
  #pragma unroll
  for(int t=0; t<5; ++t){
    float s = ksacc[t];
    s += __shfl_xor(s, 16); s += __shfl_xor(s, 32);
    if(g == 0) ex[mtp*320 + (fqp*5 + t)*16 + q] = s;
  }
  __syncthreads();
  for(int i = tid; i < 288; i += 1024)
    ksum_part[(size_t)bid*288 + i] = ex[i] + ex[320+i] + ex[640+i] + ex[960+i];
}

// ---------------- reduce: sum 8 chunk partials -> ctx hi (e-major) + ksum ----------------
__global__ void fa21_reduce(const float* __restrict__ ctx_part, const float* __restrict__ ksum_part,
                            short* __restrict__ cth, float* __restrict__ ksum){
  int h = blockIdx.x, tid = threadIdx.x;
  for(int idx = tid; idx < 288*64; idx += 256){
    float s = 0.f;
    #pragma unroll
    for(int c=0;c<8;++c) s += ctx_part[(size_t)(h + 32*c)*288*64 + idx];
    int f = idx >> 6, e = idx & 63;
    cth[(size_t)h*64*288 + e*288 + f] = (short)bf16rne(s);
  }
  for(int idx = tid; idx < 288; idx += 256){
    float s = 0.f;
    #pragma unroll
    for(int c=0;c<8;++c) s += ksum_part[(size_t)(h + 32*c)*288 + idx];
    ksum[h*288 + idx] = s;
  }
}

// ---------------- phase 2: qp -> out (swapped phi, barrier-free loop) ----------------
// grid 512 = 32 heads x 16 chunks, 512 thr (8 waves), 4 iters x 128 rows (wave: 16).
// S^T[f][n]: mfma(A=proj, B=X) -> lane (q,g) holds S[f=ftl*16+4g+i][n=q].
// rowmax/diag/denom per-lane (n=q). pass1 = max only; pass2 recompute + exp +
// in-register frag assembly (8 shfl/pair) + out MFMA with ctxH from LDS.
// LDS: projH 36864 swz + ctxH [64][592] 37888 + ksum 1184 = 75936 -> 2 blocks/CU.
__global__ __launch_bounds__(512) void fa21_p2(
    const float* __restrict__ qin,
    const short* __restrict__ pjh,
    const short* __restrict__ cth,
    const float* __restrict__ ksum, float* __restrict__ outp,
    float qoff, float qeps, float diagc){
  extern __shared__ char smem[];
  char* sph = smem;                      // 36864
  char* sct = smem + 36864;              // 37888
  float* sks = (float*)(smem + 74752);   // 1184
  const int tid = threadIdx.x;
  const int w = tid >> 6, lane = tid & 63, g = lane >> 4, q = lane & 15;
  const int bid = blockIdx.x;
  const int head = bid & 31, chunk = bid >> 5;
  // stage projH (swz), ctxH (e-major, 592B stride), ksum
  for(int i = tid; i < 2304; i += 512){
    int f = i >> 3;
    int byt = (f*128 + (i & 7)*16) ^ ((f & 7) << 4);
    *(s16x8*)(sph + byt) = ((const s16x8*)pjh)[i];
  }
  for(int i = tid; i < 2304; i += 512){
    int base = i*8;
    int e = base / 288, fo = base - e*288;
    *(s16x8*)(sct + e*592 + fo*2) = ((const s16x8*)(cth + (size_t)head*18432))[i];
  }
  if(tid < 296) sks[tid] = (tid < 288) ? ksum[head*288 + tid] : 0.f;
  const float* qbase = qin + (size_t)head*8192*64;
  float* obase = outp + (size_t)head*8192*64;
  __syncthreads();
  #pragma unroll 1
  for(int it=0; it<4; ++it){
    const int row0 = chunk*512 + it*128 + w*16;
    // ---- X B-frags: lane reads ITS row n = q
    s16x8 xh[2], xl[2];
    float diag;
    {
      const float* rp = qbase + (size_t)(row0 + q)*64;
      float ss = 0.f;
      #pragma unroll
      for(int ks=0; ks<2; ++ks){
        float4 a = *(const float4*)(rp + ks*32 + g*8);
        float4 b = *(const float4*)(rp + ks*32 + g*8 + 4);
        float vv[8] = {a.x,a.y,a.z,a.w,b.x,b.y,b.z,b.w};
        #pragma unroll
        for(int j=0;j<8;++j) ss += vv[j]*vv[j];
        cvt_hl8(vv, xh[ks], xl[ks]);
      }
      ss += __shfl_xor(ss, 16); ss += __shfl_xor(ss, 32);
      diag = ss * diagc;   // full row-sum, valid in every lane (row = q)
    }
    // ---- pass 1: rowmax over real features (tiles 0..16; 17 is all-pad)
    float m = -3e38f;
    #pragma unroll
    for(int ftl=0; ftl<17; ++ftl){
      f32x4 St = {0.f,0.f,0.f,0.f};
      #pragma unroll
      for(int ks=0; ks<2; ++ks){
        const int f = ftl*16 + q;
        int byt = (f*128 + ks*64 + g*16) ^ ((f & 7) << 4);
        s16x8 pa = *(const s16x8*)(sph + byt);
        St = MFMA16(pa, xh[ks], St);
        St = MFMA16(pa, xl[ks], St);
      }
      if(ftl < 16){
        m = fmaxf(m, fmaxf(fmaxf(St[0], St[1]), fmaxf(St[2], St[3])));
      }else{
        #pragma unroll
        for(int i=0;i<4;++i){
          float v = (4*g + i < 10) ? St[i] : -3e38f;  // f = 256+4g+i < 266
          m = fmaxf(m, v);
        }
      }
    }
    m = fmaxf(m, __shfl_xor(m, 16));
    m = fmaxf(m, __shfl_xor(m, 32));
    const float dro = diag + m - qoff;   // per-lane (n = q)
    // ---- pass 2: recompute per pair, exp, frag assembly, out MFMA
    float dnp = 0.f;
    f32x4 oacc[4];
    #pragma unroll
    for(int e2=0;e2<4;++e2){ f32x4 z = {0.f,0.f,0.f,0.f}; oacc[e2] = z; }
    const int a2 = (g & 1)*2;
    const int s0 = q + 16*a2, s1 = s0 + 16;
    #pragma unroll
    for(int p=0; p<9; ++p){
      unsigned u01a, u23a, u01b, u23b;
      #pragma unroll
      for(int t=0; t<2; ++t){
        const int ftl = 2*p + t;
        f32x4 St = {0.f,0.f,0.f,0.f};
        #pragma unroll
        for(int ks=0; ks<2; ++ks){
          const int f = ftl*16 + q;
          int byt = (f*128 + ks*64 + g*16) ^ ((f & 7) << 4);
          s16x8 pa = *(const s16x8*)(sph + byt);
          St = MFMA16(pa, xh[ks], St);
          St = MFMA16(pa, xl[ks], St);
        }
        float4 kv = *(const float4*)((const char*)sks + (ftl*16 + 4*g)*4);
        float pe[4];
        #pragma unroll
        for(int i=0;i<4;++i){
          pe[i] = exp2f(St[i] - dro) + qeps;   // padded f: ctx/ksum rows are 0
          dnp += pe[i] * ((&kv.x)[i]);
        }
        unsigned lo = (unsigned)bf16rne(pe[0]) | ((unsigned)bf16rne(pe[1]) << 16);
        unsigned hi = (unsigned)bf16rne(pe[2]) | ((unsigned)bf16rne(pe[3]) << 16);
        if(t == 0){ u01a = lo; u23a = hi; } else { u01b = lo; u23b = hi; }
      }
      // assemble B-frag: lane (q,g) needs qp[f = p*32 + 8g + j][n=q], j=0..7
      unsigned w0a = __shfl(u01a, s0), w0b = __shfl(u01b, s0);
      unsigned w1a = __shfl(u23a, s0), w1b = __shfl(u23b, s0);
      unsigned w2a = __shfl(u01a, s1), w2b = __shfl(u01b, s1);
      unsigned w3a = __shfl(u23a, s1), w3b = __shfl(u23b, s1);
      const bool t0 = (g < 2);
      unsigned fw[4];
      fw[0] = t0 ? w0a : w0b;
      fw[1] = t0 ? w1a : w1b;
      fw[2] = t0 ? w2a : w2b;
      fw[3] = t0 ? w3a : w3b;
      s16x8 qf;
      #pragma unroll
      for(int j=0;j<4;++j){
        qf[2*j]   = (short)(fw[j] & 0xffffu);
        qf[2*j+1] = (short)(fw[j] >> 16);
      }
      // out: for each e-tile, A = ctxH rows e, k = f-pair
      #pragma unroll
      for(int e2=0; e2<4; ++e2){
        int byt = (e2*16 + q)*592 + p*64 + g*16;
        s16x8 ca = *(const s16x8*)(sct + byt);
        oacc[e2] = MFMA16(ca, qf, oacc[e2]);
      }
    }
    // ---- denom (sum g-parts), scale, store (C: row = e-local, col = n = q)
    dnp += __shfl_xor(dnp, 16);
    dnp += __shfl_xor(dnp, 32);
    const float dinv = 1.0f / (dnp + 1e-8f);
    #pragma unroll
    for(int e2=0; e2<4; ++e2){
      float4 o;
      o.x = oacc[e2][0]*dinv; o.y = oacc[e2][1]*dinv;
      o.z = oacc[e2][2]*dinv; o.w = oacc[e2][3]*dinv;
      *(float4*)(obase + (size_t)(row0 + q)*64 + e2*16 + 4*g) = o;
    }
  }
}

extern "C" void kernel_launch(void* const* d_in, const int* in_sizes, int n_in,
                              void* d_out, int out_size, void* d_ws, size_t ws_size,
                              hipStream_t stream){
  const float* q    = (const float*)d_in[0];
  const float* k    = (const float*)d_in[1];
  const float* v    = (const float*)d_in[2];
  const float* proj = (const float*)d_in[3];
  float* out = (float*)d_out;
  char* ws = (char*)d_ws;
  short* wproj_h = (short*)(ws);
  short* wproj_l = (short*)(ws + 36864);
  float* wctx    = (float*)(ws + 73728);
  float* wksump  = (float*)(ws + 18948096);          // 73728 + 256*288*64*4
  short* wct_h   = (short*)(ws + 19243008);          // + 256*288*4
  float* wksum   = (float*)(ws + 20422656);          // + 32*64*288*2

  const double LOG2E = 1.4426950408889634;
  const double ln_ratio = -0.5*log(266.0);
  float pscale = (float)(pow(64.0, -0.25) * LOG2E);
  float diagc  = (float)(0.0625 * LOG2E);
  float koff   = (float)((1e-4 + ln_ratio) * LOG2E);
  float qoff   = (float)(ln_ratio * LOG2E);
  float qeps   = (float)(1e-4 / sqrt(266.0));

  hipFuncSetAttribute((const void*)fa21_p1, hipFuncAttributeMaxDynamicSharedMemorySize, 122880);
  hipFuncSetAttribute((const void*)fa21_p2, hipFuncAttributeMaxDynamicSharedMemorySize, 75936);

  fa21_prep<<<72, 256, 0, stream>>>(proj, wproj_h, wproj_l, pscale);
  fa21_p1<<<256, 1024, 122880, stream>>>(k, v, wproj_h, wproj_l, wctx, wksump, koff, diagc);
  fa21_reduce<<<32, 256, 0, stream>>>(wctx, wksump, wct_h, wksum);
  fa21_p2<<<512, 512, 75936, stream>>>(q, wproj_h, wct_h, wksum, out, qoff, qeps, diagc);
}

// Round 8
// 278.776 us; speedup vs baseline: 2.5724x; 1.3743x over previous
//
#include <hip/hip_runtime.h>
#include <math.h>

// FAVOR+ (Performer) non-causal linear attention, b=4 h=8 n=8192 d=64 f=266.
// Round 8: p1 = round-7 kernel (proven ~52us). p2 rebuilt on the same skeleton:
// 1024 thr / 16 waves (4/SIMD), wave = (row-tile x f-quarter), S[5] per wave,
// projH frags persistent in 40 VGPRs, projL + ctxH + qp-hi in LDS (124KB),
// cross-quarter rowmax/denom via LDS, 3 barriers/iter. Designed VGPR <= ~115.

typedef __attribute__((ext_vector_type(8))) short s16x8;
typedef __attribute__((ext_vector_type(4))) float f32x4;

#define MFMA16(a,b,c) __builtin_amdgcn_mfma_f32_16x16x32_bf16((a),(b),(c),0,0,0)

__device__ __forceinline__ unsigned short bf16rne(float x){
  unsigned u = __float_as_uint(x);
  u = u + 0x7fffu + ((u >> 16) & 1u);
  return (unsigned short)(u >> 16);
}
__device__ __forceinline__ float bf16tof(unsigned short h){
  return __uint_as_float(((unsigned)h) << 16);
}
__device__ __forceinline__ void cvt_hl8(const float v[8], s16x8& h, s16x8& l){
  #pragma unroll
  for(int j=0;j<8;++j){
    unsigned short hh = bf16rne(v[j]);
    h[j] = (short)hh;
    l[j] = (short)bf16rne(v[j] - bf16tof(hh));
  }
}

// ---------------- prep: scaled/padded proj hi/lo (288 rows) ----------------
__global__ void fa21_prep(const float* __restrict__ proj, short* __restrict__ ph,
                          short* __restrict__ pl, float pscale){
  int idx = blockIdx.x*256 + threadIdx.x;
  if(idx >= 288*64) return;
  int f = idx >> 6, dc = idx & 63;
  float v = (f < 266) ? proj[f*64 + dc]*pscale : 0.f;
  unsigned short hh = bf16rne(v);
  ph[idx] = (short)hh;
  pl[idx] = (short)bf16rne(v - bf16tof(hh));
}

// ---------------- phase 1: kp -> context partials + ksum partials ----------------
// (unchanged from round 7 — measured ~52us)
__global__ __launch_bounds__(1024,1) void fa21_p1(
    const float* __restrict__ kin, const float* __restrict__ vin,
    const short* __restrict__ pjh, const short* __restrict__ pjl,
    float* __restrict__ ctx_part, float* __restrict__ ksum_part,
    float koff, float diagc){
  extern __shared__ char smem[];
  char* sph = smem;                     // 40960
  char* spl = smem + 40960;             // 40960
  char* skh = smem + 81920;             // 40960 (kp), overlaid by ex[] at end
  float* ex = (float*)(smem + 81920);
  const int tid = threadIdx.x;
  const int w = tid >> 6, lane = tid & 63, g = lane >> 4, q = lane & 15;
  const int bid = blockIdx.x;
  const int head = bid & 31, chunk = bid >> 5;
  for(int i = tid; i < 2560; i += 1024){
    int f = i >> 3;
    int byt = (f*128 + (i & 7)*16) ^ ((f & 7) << 4);
    s16x8 vh8 = {0,0,0,0,0,0,0,0}, vl8 = {0,0,0,0,0,0,0,0};
    if(f < 288){
      vh8 = ((const s16x8*)pjh)[i];
      vl8 = ((const s16x8*)pjl)[i];
    }
    *(s16x8*)(sph + byt) = vh8;
    *(s16x8*)(spl + byt) = vl8;
  }
  const int mtp = w & 3, fqp = w >> 2;
  const int et  = w & 3, fqc = w >> 2;
  f32x4 acc[5];
  #pragma unroll
  for(int a=0;a<5;++a){ f32x4 z = {0.f,0.f,0.f,0.f}; acc[a] = z; }
  float ksacc[5] = {0.f,0.f,0.f,0.f,0.f};
  const float* kbase = kin + (size_t)head*8192*64;
  const float* vbase = vin + (size_t)head*8192*64;
  float4 xa0, xb0, xa1, xb1;
  {
    const float* rp = kbase + (size_t)(chunk*1024 + mtp*16 + q)*64;
    xa0 = *(const float4*)(rp + g*8);       xb0 = *(const float4*)(rp + g*8 + 4);
    xa1 = *(const float4*)(rp + 32 + g*8);  xb1 = *(const float4*)(rp + 32 + g*8 + 4);
  }
  __syncthreads();
  #pragma unroll 1
  for(int it = 0; it < 16; ++it){
    const int nb = chunk*1024 + it*64;
    s16x8 xh[2], xl[2];
    float diag;
    {
      float v0[8] = {xa0.x,xa0.y,xa0.z,xa0.w,xb0.x,xb0.y,xb0.z,xb0.w};
      float v1[8] = {xa1.x,xa1.y,xa1.z,xa1.w,xb1.x,xb1.y,xb1.z,xb1.w};
      float ss = 0.f;
      #pragma unroll
      for(int j=0;j<8;++j){ ss += v0[j]*v0[j]; ss += v1[j]*v1[j]; }
      cvt_hl8(v0, xh[0], xl[0]);
      cvt_hl8(v1, xh[1], xl[1]);
      ss += __shfl_xor(ss, 16); ss += __shfl_xor(ss, 32);
      diag = ss * diagc;
    }
    float dro[4];
    #pragma unroll
    for(int i=0;i<4;++i) dro[i] = __shfl(diag, 4*g + i) - koff;
    s16x8 vh[2], vl[2];
    {
      const int e = et*16 + q;
      #pragma unroll
      for(int ks=0; ks<2; ++ks){
        float vv[8];
        #pragma unroll
        for(int i2=0;i2<8;++i2) vv[i2] = vbase[(size_t)(nb + ks*32 + 8*g + i2)*64 + e];
        cvt_hl8(vv, vh[ks], vl[ks]);
      }
    }
    f32x4 S[5];
    #pragma unroll
    for(int t=0;t<5;++t){ f32x4 z = {0.f,0.f,0.f,0.f}; S[t] = z; }
    #pragma unroll
    for(int t=0; t<5; ++t){
      const int f = (fqp*5 + t)*16 + q;
      #pragma unroll
      for(int ks=0; ks<2; ++ks){
        int byt = (f*128 + ks*64 + g*16) ^ ((f & 7) << 4);
        s16x8 bph = *(const s16x8*)(sph + byt);
        s16x8 bpl = *(const s16x8*)(spl + byt);
        S[t] = MFMA16(xh[ks], bph, S[t]);
        S[t] = MFMA16(xl[ks], bph, S[t]);
        S[t] = MFMA16(xh[ks], bpl, S[t]);
      }
    }
    #pragma unroll
    for(int t=0; t<5; ++t){
      const int f = (fqp*5 + t)*16 + q;
      const bool live = (f < 266);
      float p[4];
      #pragma unroll
      for(int i=0;i<4;++i){
        float e2 = exp2f(S[t][i] - dro[i]);
        p[i] = live ? e2 : 0.f;
      }
      ksacc[t] += p[0]+p[1]+p[2]+p[3];
      uint2 hv;
      hv.x = (unsigned)bf16rne(p[0]) | ((unsigned)bf16rne(p[1]) << 16);
      hv.y = (unsigned)bf16rne(p[2]) | ((unsigned)bf16rne(p[3]) << 16);
      int byt = (f*128 + (mtp*16 + 4*g)*2) ^ ((f & 7) << 4);
      *(uint2*)(skh + byt) = hv;
    }
    {
      const int itn = (it + 1) & 15;
      const float* rp = kbase + (size_t)(chunk*1024 + itn*64 + mtp*16 + q)*64;
      xa0 = *(const float4*)(rp + g*8);       xb0 = *(const float4*)(rp + g*8 + 4);
      xa1 = *(const float4*)(rp + 32 + g*8);  xb1 = *(const float4*)(rp + 32 + g*8 + 4);
    }
    __syncthreads();   // kp ready
    #pragma unroll
    for(int fm=0; fm<5; ++fm){
      const int fg = (fqc*5 + fm)*16 + q;
      #pragma unroll
      for(int ks=0; ks<2; ++ks){
        int byt = (fg*128 + ks*64 + g*16) ^ ((fg & 7) << 4);
        s16x8 kf = *(const s16x8*)(skh + byt);
        acc[fm] = MFMA16(kf, vh[ks], acc[fm]);
        acc[fm] = MFMA16(kf, vl[ks], acc[fm]);
      }
    }
    __syncthreads();   // kp LDS reusable
  }
  {
    float* cp = ctx_part + (size_t)bid*288*64;
    #pragma unroll
    for(int fm=0; fm<5; ++fm){
      const int gt = fqc*5 + fm;
      if(gt < 18){
        #pragma unroll
        for(int i=0;i<4;++i){
          int f = gt*16 + 4*g + i;
          cp[f*64 + et*16 + q] = acc[fm][i];
        }
      }
    }
  }
  #pragma unroll
  for(int t=0; t<5; ++t){
    float s = ksacc[t];
    s += __shfl_xor(s, 16); s += __shfl_xor(s, 32);
    if(g == 0) ex[mtp*320 + (fqp*5 + t)*16 + q] = s;
  }
  __syncthreads();
  for(int i = tid; i < 288; i += 1024)
    ksum_part[(size_t)bid*288 + i] = ex[i] + ex[320+i] + ex[640+i] + ex[960+i];
}

// ---------------- reduce: sum 8 chunk partials -> ctx hi (e-major) + ksum ----------------
__global__ void fa21_reduce(const float* __restrict__ ctx_part, const float* __restrict__ ksum_part,
                            short* __restrict__ cth, float* __restrict__ ksum){
  int h = blockIdx.x, tid = threadIdx.x;
  for(int idx = tid; idx < 288*64; idx += 256){
    float s = 0.f;
    #pragma unroll
    for(int c=0;c<8;++c) s += ctx_part[(size_t)(h + 32*c)*288*64 + idx];
    int f = idx >> 6, e = idx & 63;
    cth[(size_t)h*64*288 + e*288 + f] = (short)bf16rne(s);
  }
  for(int idx = tid; idx < 288; idx += 256){
    float s = 0.f;
    #pragma unroll
    for(int c=0;c<8;++c) s += ksum_part[(size_t)(h + 32*c)*288 + idx];
    ksum[h*288 + idx] = s;
  }
}

// ---------------- phase 2: qp -> out (p1-skeleton clone) ----------------
// grid 256 = 32 heads x 8 chunks, 1024 thr (16 waves), 16 iters x 64 rows.
// phi role: (mt4 = w&3 row-tile, fq = w>>2 f-quarter of 5 tiles, f-pad 320).
// out role: (mt4 rows, et = fq e-tile). projH frags persistent in VGPRs (40),
// projL in LDS (3-product phi), qp-hi n-major LDS, ctxH e-major LDS.
// LDS: projL 40960 + ctxH 64x656 = 41984 + qp 64x656 = 41984 + rmx 1024 + dnb 1024
//    = 126976 -> 1 block/CU, 4 waves/SIMD.
__global__ __launch_bounds__(1024,1) void fa21_p2(
    const float* __restrict__ qin,
    const short* __restrict__ pjh, const short* __restrict__ pjl,
    const short* __restrict__ cth,
    const float* __restrict__ ksum, float* __restrict__ outp,
    float qoff, float qeps, float diagc){
  extern __shared__ char smem[];
  char* spl = smem;                        // 40960 projL swz
  char* sct = smem + 40960;                // 41984 ctxH [64][328 shorts]
  char* sqp = smem + 82944;                // 41984 qp-hi [64][328 shorts]
  float* rmx = (float*)(smem + 124928);    // [4][64]
  float* dnb = (float*)(smem + 125952);    // [4][64]
  const int tid = threadIdx.x;
  const int w = tid >> 6, lane = tid & 63, g = lane >> 4, q = lane & 15;
  const int bid = blockIdx.x;
  const int head = bid & 31, chunk = bid >> 5;
  const int mt4 = w & 3, fq = w >> 2;
  // ---- stage projL (320-pad, swz)
  for(int i = tid; i < 2560; i += 1024){
    int f = i >> 3;
    int byt = (f*128 + (i & 7)*16) ^ ((f & 7) << 4);
    s16x8 vl8 = {0,0,0,0,0,0,0,0};
    if(f < 288) vl8 = ((const s16x8*)pjl)[i];
    *(s16x8*)(spl + byt) = vl8;
  }
  // ---- stage ctxH e-major [64][320->328 pad]
  {
    const short* cb = cth + (size_t)head*18432;
    for(int i = tid; i < 2560; i += 1024){
      int e = i / 40, j = i - e*40;
      int f0 = j*8;
      s16x8 v8 = {0,0,0,0,0,0,0,0};
      if(f0 < 288) v8 = *(const s16x8*)(cb + e*288 + f0);
      *(s16x8*)(sct + e*656 + f0*2) = v8;
    }
  }
  // ---- persistent projH B-frags for this wave's f-quarter (40 VGPR)
  s16x8 bph[5][2];
  #pragma unroll
  for(int t=0; t<5; ++t){
    const int f = (fq*5 + t)*16 + q;
    #pragma unroll
    for(int ks=0; ks<2; ++ks){
      s16x8 v8 = {0,0,0,0,0,0,0,0};
      if(f < 288) v8 = *(const s16x8*)(pjh + f*64 + ks*32 + g*8);
      bph[t][ks] = v8;
    }
  }
  float ksv[5];
  #pragma unroll
  for(int t=0; t<5; ++t){
    const int f = (fq*5 + t)*16 + q;
    ksv[t] = (f < 288) ? ksum[head*288 + f] : 0.f;
  }
  const float* qbase = qin + (size_t)head*8192*64;
  float* obase = outp + (size_t)head*8192*64;
  __syncthreads();
  #pragma unroll 1
  for(int it=0; it<16; ++it){
    const int nb = chunk*1024 + it*64;
    // ---- X A-frags: rows mt4*16+q
    s16x8 xh[2], xl[2];
    float diag;
    {
      const float* rp = qbase + (size_t)(nb + mt4*16 + q)*64;
      float ss = 0.f;
      #pragma unroll
      for(int ks=0; ks<2; ++ks){
        float4 a = *(const float4*)(rp + ks*32 + g*8);
        float4 b = *(const float4*)(rp + ks*32 + g*8 + 4);
        float vv[8] = {a.x,a.y,a.z,a.w,b.x,b.y,b.z,b.w};
        #pragma unroll
        for(int j=0;j<8;++j) ss += vv[j]*vv[j];
        cvt_hl8(vv, xh[ks], xl[ks]);
      }
      ss += __shfl_xor(ss, 16); ss += __shfl_xor(ss, 32);
      diag = ss * diagc;
    }
    // ---- phi: 5 f-tiles, 3-product (projH from regs, projL from LDS)
    f32x4 S[5];
    #pragma unroll
    for(int t=0;t<5;++t){ f32x4 z = {0.f,0.f,0.f,0.f}; S[t] = z; }
    #pragma unroll
    for(int t=0; t<5; ++t){
      const int f = (fq*5 + t)*16 + q;
      #pragma unroll
      for(int ks=0; ks<2; ++ks){
        int byt = (f*128 + ks*64 + g*16) ^ ((f & 7) << 4);
        s16x8 bpl = *(const s16x8*)(spl + byt);
        S[t] = MFMA16(xh[ks], bph[t][ks], S[t]);
        S[t] = MFMA16(xl[ks], bph[t][ks], S[t]);
        S[t] = MFMA16(xh[ks], bpl, S[t]);
      }
    }
    // ---- rowmax partial (this f-quarter) -> LDS
    #pragma unroll
    for(int i=0;i<4;++i){
      float m = -3e38f;
      #pragma unroll
      for(int t=0; t<5; ++t){
        const int f = (fq*5 + t)*16 + q;
        float v = (f < 266) ? S[t][i] : -3e38f;
        m = fmaxf(m, v);
      }
      m = fmaxf(m, __shfl_xor(m, 1));
      m = fmaxf(m, __shfl_xor(m, 2));
      m = fmaxf(m, __shfl_xor(m, 4));
      m = fmaxf(m, __shfl_xor(m, 8));
      if(q == i) rmx[fq*64 + mt4*16 + 4*g + i] = m;
    }
    __syncthreads();  // bar1: rowmax ready
    float dro[4];
    #pragma unroll
    for(int i=0;i<4;++i){
      int row = mt4*16 + 4*g + i;
      float rm = fmaxf(fmaxf(rmx[row], rmx[64 + row]),
                       fmaxf(rmx[128 + row], rmx[192 + row]));
      dro[i] = __shfl(diag, 4*g + i) + rm - qoff;
    }
    // ---- qp = exp2(S - dro) + qeps (masked), denom partial, hi -> LDS n-major
    float dnp[4] = {0.f,0.f,0.f,0.f};
    #pragma unroll
    for(int t=0; t<5; ++t){
      const int f = (fq*5 + t)*16 + q;
      const bool live = (f < 266);
      #pragma unroll
      for(int i=0;i<4;++i){
        float e2 = exp2f(S[t][i] - dro[i]) + qeps;
        float pe = live ? e2 : 0.f;
        dnp[i] += pe * ksv[t];
        int n = mt4*16 + 4*g + i;
        *(short*)(sqp + n*656 + f*2) = (short)bf16rne(pe);
      }
    }
    #pragma unroll
    for(int i=0;i<4;++i){
      float s = dnp[i];
      s += __shfl_xor(s, 1); s += __shfl_xor(s, 2);
      s += __shfl_xor(s, 4); s += __shfl_xor(s, 8);
      if(q == i) dnb[fq*64 + mt4*16 + 4*g + i] = s;
    }
    __syncthreads();  // bar2: qp + denom ready
    // ---- out GEMM: wave (mt4 rows, et=fq e-tile): 16x16, K=320 (10 tiles)
    f32x4 oacc = {0.f,0.f,0.f,0.f};
    #pragma unroll
    for(int ks=0; ks<10; ++ks){
      s16x8 ah = *(const s16x8*)(sqp + (mt4*16 + q)*656 + ks*64 + 16*g);
      s16x8 ch = *(const s16x8*)(sct + (fq*16 + q)*656 + ks*64 + 16*g);
      oacc = MFMA16(ah, ch, oacc);
    }
    #pragma unroll
    for(int i=0;i<4;++i){
      int row = mt4*16 + 4*g + i;
      float den = dnb[row] + dnb[64+row] + dnb[128+row] + dnb[192+row] + 1e-8f;
      obase[(size_t)(nb + row)*64 + fq*16 + q] = oacc[i] / den;
    }
    __syncthreads();  // bar3: qp/rmx/dnb reusable
  }
}

extern "C" void kernel_launch(void* const* d_in, const int* in_sizes, int n_in,
                              void* d_out, int out_size, void* d_ws, size_t ws_size,
                              hipStream_t stream){
  const float* q    = (const float*)d_in[0];
  const float* k    = (const float*)d_in[1];
  const float* v    = (const float*)d_in[2];
  const float* proj = (const float*)d_in[3];
  float* out = (float*)d_out;
  char* ws = (char*)d_ws;
  short* wproj_h = (short*)(ws);
  short* wproj_l = (short*)(ws + 36864);
  float* wctx    = (float*)(ws + 73728);
  float* wksump  = (float*)(ws + 18948096);          // 73728 + 256*288*64*4
  short* wct_h   = (short*)(ws + 19243008);          // + 256*288*4
  float* wksum   = (float*)(ws + 20422656);          // + 32*64*288*2

  const double LOG2E = 1.4426950408889634;
  const double ln_ratio = -0.5*log(266.0);
  float pscale = (float)(pow(64.0, -0.25) * LOG2E);
  float diagc  = (float)(0.0625 * LOG2E);
  float koff   = (float)((1e-4 + ln_ratio) * LOG2E);
  float qoff   = (float)(ln_ratio * LOG2E);
  float qeps   = (float)(1e-4 / sqrt(266.0));

  hipFuncSetAttribute((const void*)fa21_p1, hipFuncAttributeMaxDynamicSharedMemorySize, 122880);
  hipFuncSetAttribute((const void*)fa21_p2, hipFuncAttributeMaxDynamicSharedMemorySize, 126976);

  fa21_prep<<<72, 256, 0, stream>>>(proj, wproj_h, wproj_l, pscale);
  fa21_p1<<<256, 1024, 122880, stream>>>(k, v, wproj_h, wproj_l, wctx, wksump, koff, diagc);
  fa21_reduce<<<32, 256, 0, stream>>>(wctx, wksump, wct_h, wksum);
  fa21_p2<<<256, 1024, 126976, stream>>>(q, wproj_h, wproj_l, wct_h, wksum, out,
                                         qoff, qeps, diagc);
}

// Round 9
// 233.036 us; speedup vs baseline: 3.0773x; 1.1963x over previous
//
#include <hip/hip_runtime.h>
#include <math.h>

// FAVOR+ (Performer) non-causal linear attention, b=4 h=8 n=8192 d=64 f=266.
// Round 9: p1 unchanged (proven). p2 rebuilt with swapped-operand phi
// (mfma(proj, X) -> S^T: n on lane col, f on 4g+i): per-lane rowmax/denom
// (2 shfl instead of 16-lane trees), packed b64 qp writes (5 vs 20 scalar),
// b128 denominator reads, 2 barriers/iter. reduce kernel: 32 -> 256 blocks.

typedef __attribute__((ext_vector_type(8))) short s16x8;
typedef __attribute__((ext_vector_type(4))) float f32x4;

#define MFMA16(a,b,c) __builtin_amdgcn_mfma_f32_16x16x32_bf16((a),(b),(c),0,0,0)

__device__ __forceinline__ unsigned short bf16rne(float x){
  unsigned u = __float_as_uint(x);
  u = u + 0x7fffu + ((u >> 16) & 1u);
  return (unsigned short)(u >> 16);
}
__device__ __forceinline__ float bf16tof(unsigned short h){
  return __uint_as_float(((unsigned)h) << 16);
}
__device__ __forceinline__ void cvt_hl8(const float v[8], s16x8& h, s16x8& l){
  #pragma unroll
  for(int j=0;j<8;++j){
    unsigned short hh = bf16rne(v[j]);
    h[j] = (short)hh;
    l[j] = (short)bf16rne(v[j] - bf16tof(hh));
  }
}

// ---------------- prep: scaled/padded proj hi/lo (288 rows) ----------------
__global__ void fa21_prep(const float* __restrict__ proj, short* __restrict__ ph,
                          short* __restrict__ pl, float pscale){
  int idx = blockIdx.x*256 + threadIdx.x;
  if(idx >= 288*64) return;
  int f = idx >> 6, dc = idx & 63;
  float v = (f < 266) ? proj[f*64 + dc]*pscale : 0.f;
  unsigned short hh = bf16rne(v);
  ph[idx] = (short)hh;
  pl[idx] = (short)bf16rne(v - bf16tof(hh));
}

// ---------------- phase 1: kp -> context partials + ksum partials ----------------
// (unchanged from rounds 7/8 — measured ~52us)
__global__ __launch_bounds__(1024,1) void fa21_p1(
    const float* __restrict__ kin, const float* __restrict__ vin,
    const short* __restrict__ pjh, const short* __restrict__ pjl,
    float* __restrict__ ctx_part, float* __restrict__ ksum_part,
    float koff, float diagc){
  extern __shared__ char smem[];
  char* sph = smem;                     // 40960
  char* spl = smem + 40960;             // 40960
  char* skh = smem + 81920;             // 40960 (kp), overlaid by ex[] at end
  float* ex = (float*)(smem + 81920);
  const int tid = threadIdx.x;
  const int w = tid >> 6, lane = tid & 63, g = lane >> 4, q = lane & 15;
  const int bid = blockIdx.x;
  const int head = bid & 31, chunk = bid >> 5;
  for(int i = tid; i < 2560; i += 1024){
    int f = i >> 3;
    int byt = (f*128 + (i & 7)*16) ^ ((f & 7) << 4);
    s16x8 vh8 = {0,0,0,0,0,0,0,0}, vl8 = {0,0,0,0,0,0,0,0};
    if(f < 288){
      vh8 = ((const s16x8*)pjh)[i];
      vl8 = ((const s16x8*)pjl)[i];
    }
    *(s16x8*)(sph + byt) = vh8;
    *(s16x8*)(spl + byt) = vl8;
  }
  const int mtp = w & 3, fqp = w >> 2;
  const int et  = w & 3, fqc = w >> 2;
  f32x4 acc[5];
  #pragma unroll
  for(int a=0;a<5;++a){ f32x4 z = {0.f,0.f,0.f,0.f}; acc[a] = z; }
  float ksacc[5] = {0.f,0.f,0.f,0.f,0.f};
  const float* kbase = kin + (size_t)head*8192*64;
  const float* vbase = vin + (size_t)head*8192*64;
  float4 xa0, xb0, xa1, xb1;
  {
    const float* rp = kbase + (size_t)(chunk*1024 + mtp*16 + q)*64;
    xa0 = *(const float4*)(rp + g*8);       xb0 = *(const float4*)(rp + g*8 + 4);
    xa1 = *(const float4*)(rp + 32 + g*8);  xb1 = *(const float4*)(rp + 32 + g*8 + 4);
  }
  __syncthreads();
  #pragma unroll 1
  for(int it = 0; it < 16; ++it){
    const int nb = chunk*1024 + it*64;
    s16x8 xh[2], xl[2];
    float diag;
    {
      float v0[8] = {xa0.x,xa0.y,xa0.z,xa0.w,xb0.x,xb0.y,xb0.z,xb0.w};
      float v1[8] = {xa1.x,xa1.y,xa1.z,xa1.w,xb1.x,xb1.y,xb1.z,xb1.w};
      float ss = 0.f;
      #pragma unroll
      for(int j=0;j<8;++j){ ss += v0[j]*v0[j]; ss += v1[j]*v1[j]; }
      cvt_hl8(v0, xh[0], xl[0]);
      cvt_hl8(v1, xh[1], xl[1]);
      ss += __shfl_xor(ss, 16); ss += __shfl_xor(ss, 32);
      diag = ss * diagc;
    }
    float dro[4];
    #pragma unroll
    for(int i=0;i<4;++i) dro[i] = __shfl(diag, 4*g + i) - koff;
    s16x8 vh[2], vl[2];
    {
      const int e = et*16 + q;
      #pragma unroll
      for(int ks=0; ks<2; ++ks){
        float vv[8];
        #pragma unroll
        for(int i2=0;i2<8;++i2) vv[i2] = vbase[(size_t)(nb + ks*32 + 8*g + i2)*64 + e];
        cvt_hl8(vv, vh[ks], vl[ks]);
      }
    }
    f32x4 S[5];
    #pragma unroll
    for(int t=0;t<5;++t){ f32x4 z = {0.f,0.f,0.f,0.f}; S[t] = z; }
    #pragma unroll
    for(int t=0; t<5; ++t){
      const int f = (fqp*5 + t)*16 + q;
      #pragma unroll
      for(int ks=0; ks<2; ++ks){
        int byt = (f*128 + ks*64 + g*16) ^ ((f & 7) << 4);
        s16x8 bph = *(const s16x8*)(sph + byt);
        s16x8 bpl = *(const s16x8*)(spl + byt);
        S[t] = MFMA16(xh[ks], bph, S[t]);
        S[t] = MFMA16(xl[ks], bph, S[t]);
        S[t] = MFMA16(xh[ks], bpl, S[t]);
      }
    }
    #pragma unroll
    for(int t=0; t<5; ++t){
      const int f = (fqp*5 + t)*16 + q;
      const bool live = (f < 266);
      float p[4];
      #pragma unroll
      for(int i=0;i<4;++i){
        float e2 = exp2f(S[t][i] - dro[i]);
        p[i] = live ? e2 : 0.f;
      }
      ksacc[t] += p[0]+p[1]+p[2]+p[3];
      uint2 hv;
      hv.x = (unsigned)bf16rne(p[0]) | ((unsigned)bf16rne(p[1]) << 16);
      hv.y = (unsigned)bf16rne(p[2]) | ((unsigned)bf16rne(p[3]) << 16);
      int byt = (f*128 + (mtp*16 + 4*g)*2) ^ ((f & 7) << 4);
      *(uint2*)(skh + byt) = hv;
    }
    {
      const int itn = (it + 1) & 15;
      const float* rp = kbase + (size_t)(chunk*1024 + itn*64 + mtp*16 + q)*64;
      xa0 = *(const float4*)(rp + g*8);       xb0 = *(const float4*)(rp + g*8 + 4);
      xa1 = *(const float4*)(rp + 32 + g*8);  xb1 = *(const float4*)(rp + 32 + g*8 + 4);
    }
    __syncthreads();   // kp ready
    #pragma unroll
    for(int fm=0; fm<5; ++fm){
      const int fg = (fqc*5 + fm)*16 + q;
      #pragma unroll
      for(int ks=0; ks<2; ++ks){
        int byt = (fg*128 + ks*64 + g*16) ^ ((fg & 7) << 4);
        s16x8 kf = *(const s16x8*)(skh + byt);
        acc[fm] = MFMA16(kf, vh[ks], acc[fm]);
        acc[fm] = MFMA16(kf, vl[ks], acc[fm]);
      }
    }
    __syncthreads();   // kp LDS reusable
  }
  {
    float* cp = ctx_part + (size_t)bid*288*64;
    #pragma unroll
    for(int fm=0; fm<5; ++fm){
      const int gt = fqc*5 + fm;
      if(gt < 18){
        #pragma unroll
        for(int i=0;i<4;++i){
          int f = gt*16 + 4*g + i;
          cp[f*64 + et*16 + q] = acc[fm][i];
        }
      }
    }
  }
  #pragma unroll
  for(int t=0; t<5; ++t){
    float s = ksacc[t];
    s += __shfl_xor(s, 16); s += __shfl_xor(s, 32);
    if(g == 0) ex[mtp*320 + (fqp*5 + t)*16 + q] = s;
  }
  __syncthreads();
  for(int i = tid; i < 288; i += 1024)
    ksum_part[(size_t)bid*288 + i] = ex[i] + ex[320+i] + ex[640+i] + ex[960+i];
}

// ---------------- reduce: sum 8 chunk partials -> ctx hi (e-major) + ksum ----------------
// grid 256 = 32 heads x 8 e-slices (was 32 blocks -> only 32 CUs busy).
__global__ void fa21_reduce(const float* __restrict__ ctx_part, const float* __restrict__ ksum_part,
                            short* __restrict__ cth, float* __restrict__ ksum){
  int h = blockIdx.x >> 3, sl = blockIdx.x & 7, tid = threadIdx.x;
  for(int j = tid; j < 288*8; j += 256){
    int idx = sl*288*8 + j;                 // f-major chunk of the 288*64 space
    float s = 0.f;
    #pragma unroll
    for(int c=0;c<8;++c) s += ctx_part[(size_t)(h + 32*c)*288*64 + idx];
    int f = idx >> 6, e = idx & 63;
    cth[(size_t)h*64*288 + e*288 + f] = (short)bf16rne(s);
  }
  if(sl == 0){
    for(int idx = tid; idx < 288; idx += 256){
      float s = 0.f;
      #pragma unroll
      for(int c=0;c<8;++c) s += ksum_part[(size_t)(h + 32*c)*288 + idx];
      ksum[h*288 + idx] = s;
    }
  }
}

// ---------------- phase 2: qp -> out (swapped-operand phi) ----------------
// grid 256 = 32 heads x 8 chunks, 1024 thr (16 waves), 16 iters x 64 rows.
// wave = (mt4 = w&3 row-tile, fq = w>>2 f-quarter of 5 tiles, f-pad 320).
// phi: S^T = mfma(A=proj, B=X) -> lane holds S[f=(fq*5+t)*16+4g+i][n=q] for its
// row n = mt4*16+q. rowmax/denom per-lane + 2 shfl + tiny LDS cross-fq combine.
// qp written n-major as packed b64 (f-contiguous 4 per tile). out-GEMM:
// A = qp rows, B = ctxH cols (e=fq*16+q), D[n=4g+i][e=q], coalesced stores.
// LDS: projL 40960 + ctxH 64x656 41984 + qp 64x656 41984 + rmx 1024 + dnb 1024
//      + ksum 1280 = 128256 -> 1 block/CU, 4 waves/SIMD. 2 barriers/iter.
__global__ __launch_bounds__(1024,1) void fa21_p2(
    const float* __restrict__ qin,
    const short* __restrict__ pjh, const short* __restrict__ pjl,
    const short* __restrict__ cth,
    const float* __restrict__ ksum, float* __restrict__ outp,
    float qoff, float qeps, float diagc){
  extern __shared__ char smem[];
  char* spl = smem;                        // 40960 projL swz
  char* sct = smem + 40960;                // 41984 ctxH [64 e][656B]
  char* sqp = smem + 82944;                // 41984 qp-hi [64 n][656B]
  float* rmx = (float*)(smem + 124928);    // [4 fq][64 n]
  float* dnb = (float*)(smem + 125952);    // [4 fq][64 n]
  float* sks = (float*)(smem + 126976);    // [320]
  const int tid = threadIdx.x;
  const int w = tid >> 6, lane = tid & 63, g = lane >> 4, q = lane & 15;
  const int bid = blockIdx.x;
  const int head = bid & 31, chunk = bid >> 5;
  const int mt4 = w & 3, fq = w >> 2;
  // ---- stage projL (320-pad, swz)
  for(int i = tid; i < 2560; i += 1024){
    int f = i >> 3;
    int byt = (f*128 + (i & 7)*16) ^ ((f & 7) << 4);
    s16x8 vl8 = {0,0,0,0,0,0,0,0};
    if(f < 288) vl8 = ((const s16x8*)pjl)[i];
    *(s16x8*)(spl + byt) = vl8;
  }
  // ---- stage ctxH e-major [64][320->328 pad]
  {
    const short* cb = cth + (size_t)head*18432;
    for(int i = tid; i < 2560; i += 1024){
      int e = i / 40, j = i - e*40;
      int f0 = j*8;
      s16x8 v8 = {0,0,0,0,0,0,0,0};
      if(f0 < 288) v8 = *(const s16x8*)(cb + e*288 + f0);
      *(s16x8*)(sct + e*656 + f0*2) = v8;
    }
  }
  // ---- stage ksum [320]
  for(int i = tid; i < 320; i += 1024) sks[i] = (i < 288) ? ksum[head*288 + i] : 0.f;
  // ---- persistent projH A-frags for this wave's f-quarter (40 VGPR)
  s16x8 aph[5][2];
  #pragma unroll
  for(int t=0; t<5; ++t){
    const int f = (fq*5 + t)*16 + q;
    #pragma unroll
    for(int ks=0; ks<2; ++ks){
      s16x8 v8 = {0,0,0,0,0,0,0,0};
      if(f < 288) v8 = *(const s16x8*)(pjh + f*64 + ks*32 + g*8);
      aph[t][ks] = v8;
    }
  }
  const float* qbase = qin + (size_t)head*8192*64;
  float* obase = outp + (size_t)head*8192*64;
  __syncthreads();
  #pragma unroll 1
  for(int it=0; it<16; ++it){
    const int nb = chunk*1024 + it*64;
    // ---- X B-frags: lane reads ITS row n = mt4*16+q (k = d contiguous)
    s16x8 xh[2], xl[2];
    float diag;
    {
      const float* rp = qbase + (size_t)(nb + mt4*16 + q)*64;
      float ss = 0.f;
      #pragma unroll
      for(int ks=0; ks<2; ++ks){
        float4 a = *(const float4*)(rp + ks*32 + g*8);
        float4 b = *(const float4*)(rp + ks*32 + g*8 + 4);
        float vv[8] = {a.x,a.y,a.z,a.w,b.x,b.y,b.z,b.w};
        #pragma unroll
        for(int j=0;j<8;++j) ss += vv[j]*vv[j];
        cvt_hl8(vv, xh[ks], xl[ks]);
      }
      ss += __shfl_xor(ss, 16); ss += __shfl_xor(ss, 32);
      diag = ss * diagc;      // per-lane, row n = q (same across g)
    }
    // ---- phi swapped: S^T[f][n], 3-product (projH regs, projL LDS)
    f32x4 S[5];
    #pragma unroll
    for(int t=0;t<5;++t){ f32x4 z = {0.f,0.f,0.f,0.f}; S[t] = z; }
    #pragma unroll
    for(int t=0; t<5; ++t){
      const int f = (fq*5 + t)*16 + q;
      #pragma unroll
      for(int ks=0; ks<2; ++ks){
        int byt = (f*128 + ks*64 + g*16) ^ ((f & 7) << 4);
        s16x8 bpl = *(const s16x8*)(spl + byt);
        S[t] = MFMA16(aph[t][ks], xh[ks], S[t]);
        S[t] = MFMA16(aph[t][ks], xl[ks], S[t]);
        S[t] = MFMA16(bpl, xh[ks], S[t]);
      }
    }
    // ---- rowmax: per-lane over its 20 f-values, g-combine, cross-fq via LDS
    float m = -3e38f;
    #pragma unroll
    for(int t=0; t<5; ++t){
      const int fb = (fq*5 + t)*16 + 4*g;
      #pragma unroll
      for(int i=0;i<4;++i){
        float v = (fb + i < 266) ? S[t][i] : -3e38f;
        m = fmaxf(m, v);
      }
    }
    m = fmaxf(m, __shfl_xor(m, 16));
    m = fmaxf(m, __shfl_xor(m, 32));
    if(lane < 16) rmx[fq*64 + mt4*16 + q] = m;
    __syncthreads();  // bar1: rowmax partials ready
    const int nrow = mt4*16 + q;
    float rm = fmaxf(fmaxf(rmx[nrow], rmx[64 + nrow]),
                     fmaxf(rmx[128 + nrow], rmx[192 + nrow]));
    const float dro = diag + rm - qoff;
    // ---- qp = exp2(S - dro) + qeps (masked), per-lane denom, packed b64 write
    float dnp = 0.f;
    #pragma unroll
    for(int t=0; t<5; ++t){
      const int fb = (fq*5 + t)*16 + 4*g;
      f32x4 kv = *(const f32x4*)(sks + fb);
      float pe[4];
      #pragma unroll
      for(int i=0;i<4;++i){
        float e2 = exp2f(S[t][i] - dro) + qeps;
        pe[i] = (fb + i < 266) ? e2 : 0.f;
        dnp += pe[i] * kv[i];
      }
      uint2 hv;
      hv.x = (unsigned)bf16rne(pe[0]) | ((unsigned)bf16rne(pe[1]) << 16);
      hv.y = (unsigned)bf16rne(pe[2]) | ((unsigned)bf16rne(pe[3]) << 16);
      *(uint2*)(sqp + nrow*656 + fb*2) = hv;
    }
    dnp += __shfl_xor(dnp, 16);
    dnp += __shfl_xor(dnp, 32);
    if(lane < 16) dnb[fq*64 + nrow] = dnp;
    __syncthreads();  // bar2: qp + denom ready
    // ---- denominator for D rows (4g+i) via b128 reads
    f32x4 dsum;
    {
      f32x4 d0 = *(const f32x4*)(dnb +       mt4*16 + 4*g);
      f32x4 d1 = *(const f32x4*)(dnb +  64 + mt4*16 + 4*g);
      f32x4 d2 = *(const f32x4*)(dnb + 128 + mt4*16 + 4*g);
      f32x4 d3 = *(const f32x4*)(dnb + 192 + mt4*16 + 4*g);
      #pragma unroll
      for(int i=0;i<4;++i) dsum[i] = d0[i] + d1[i] + d2[i] + d3[i];
    }
    // ---- out GEMM: A = qp rows (mt4 tile), B = ctxH cols (e = fq*16+q), K=320
    f32x4 oacc = {0.f,0.f,0.f,0.f};
    #pragma unroll
    for(int ks=0; ks<10; ++ks){
      s16x8 ah = *(const s16x8*)(sqp + (mt4*16 + q)*656 + ks*64 + g*16);
      s16x8 ch = *(const s16x8*)(sct + (fq*16 + q)*656 + ks*64 + g*16);
      oacc = MFMA16(ah, ch, oacc);
    }
    #pragma unroll
    for(int i=0;i<4;++i){
      int row = mt4*16 + 4*g + i;
      obase[(size_t)(nb + row)*64 + fq*16 + q] = oacc[i] / (dsum[i] + 1e-8f);
    }
  }
}

extern "C" void kernel_launch(void* const* d_in, const int* in_sizes, int n_in,
                              void* d_out, int out_size, void* d_ws, size_t ws_size,
                              hipStream_t stream){
  const float* q    = (const float*)d_in[0];
  const float* k    = (const float*)d_in[1];
  const float* v    = (const float*)d_in[2];
  const float* proj = (const float*)d_in[3];
  float* out = (float*)d_out;
  char* ws = (char*)d_ws;
  short* wproj_h = (short*)(ws);
  short* wproj_l = (short*)(ws + 36864);
  float* wctx    = (float*)(ws + 73728);
  float* wksump  = (float*)(ws + 18948096);          // 73728 + 256*288*64*4
  short* wct_h   = (short*)(ws + 19243008);          // + 256*288*4
  float* wksum   = (float*)(ws + 20422656);          // + 32*64*288*2

  const double LOG2E = 1.4426950408889634;
  const double ln_ratio = -0.5*log(266.0);
  float pscale = (float)(pow(64.0, -0.25) * LOG2E);
  float diagc  = (float)(0.0625 * LOG2E);
  float koff   = (float)((1e-4 + ln_ratio) * LOG2E);
  float qoff   = (float)(ln_ratio * LOG2E);
  float qeps   = (float)(1e-4 / sqrt(266.0));

  hipFuncSetAttribute((const void*)fa21_p1, hipFuncAttributeMaxDynamicSharedMemorySize, 122880);
  hipFuncSetAttribute((const void*)fa21_p2, hipFuncAttributeMaxDynamicSharedMemorySize, 128256);

  fa21_prep<<<72, 256, 0, stream>>>(proj, wproj_h, wproj_l, pscale);
  fa21_p1<<<256, 1024, 122880, stream>>>(k, v, wproj_h, wproj_l, wctx, wksump, koff, diagc);
  fa21_reduce<<<256, 256, 0, stream>>>(wctx, wksump, wct_h, wksum);
  fa21_p2<<<256, 1024, 128256, stream>>>(q, wproj_h, wproj_l, wct_h, wksum, out,
                                         qoff, qeps, diagc);
}

// Round 10
// 202.740 us; speedup vs baseline: 3.5372x; 1.1494x over previous
//
#include <hip/hip_runtime.h>
#include <hip/hip_bf16.h>
#include <math.h>

// FAVOR+ (Performer) non-causal linear attention, b=4 h=8 n=8192 d=64 f=266.
// Round 10: round-9 structure unchanged (p1 16-wave f-quarter split; p2
// swapped-operand phi). Only change: bf16 conversion via HW converter
// (__float2bfloat16 -> v_cvt_pk_bf16_f32 pattern) instead of bit-twiddle
// (~5 insts/elem -> ~0.5), and exp2f -> __builtin_amdgcn_exp2f. p1 was
// VALU-bound on conversion scaffolding (VALUBusy 53%, ~670 VALU insts/iter).

typedef __attribute__((ext_vector_type(8))) short s16x8;
typedef __attribute__((ext_vector_type(4))) float f32x4;

#define MFMA16(a,b,c) __builtin_amdgcn_mfma_f32_16x16x32_bf16((a),(b),(c),0,0,0)

__device__ __forceinline__ unsigned short bf16rne(float x){
  union { __hip_bfloat16 b; unsigned short u; } cv;
  cv.b = __float2bfloat16(x);
  return cv.u;
}
__device__ __forceinline__ float bf16tof(unsigned short h){
  return __uint_as_float(((unsigned)h) << 16);
}
__device__ __forceinline__ float exp2_fast(float x){
#if __has_builtin(__builtin_amdgcn_exp2f)
  return __builtin_amdgcn_exp2f(x);
#else
  float r; asm("v_exp_f32 %0, %1" : "=v"(r) : "v"(x)); return r;
#endif
}
__device__ __forceinline__ void cvt_hl8(const float v[8], s16x8& h, s16x8& l){
  #pragma unroll
  for(int j=0;j<8;++j){
    unsigned short hh = bf16rne(v[j]);
    h[j] = (short)hh;
    l[j] = (short)bf16rne(v[j] - bf16tof(hh));
  }
}

// ---------------- prep: scaled/padded proj hi/lo (288 rows) ----------------
__global__ void fa21_prep(const float* __restrict__ proj, short* __restrict__ ph,
                          short* __restrict__ pl, float pscale){
  int idx = blockIdx.x*256 + threadIdx.x;
  if(idx >= 288*64) return;
  int f = idx >> 6, dc = idx & 63;
  float v = (f < 266) ? proj[f*64 + dc]*pscale : 0.f;
  unsigned short hh = bf16rne(v);
  ph[idx] = (short)hh;
  pl[idx] = (short)bf16rne(v - bf16tof(hh));
}

// ---------------- phase 1: kp -> context partials + ksum partials ----------------
// grid 256 = 32 heads x 8 chunks, 1024 thr (16 waves), 16 iters x 64 rows.
// phi role: (mtp = w&3 row-tile, fqp = w>>2 f-quarter of 5 tiles). 3-product phi.
// ctx role: (et = w&3, fqc = w>>2). 2-product ctx (kp-hi x V-hi/lo).
__global__ __launch_bounds__(1024,1) void fa21_p1(
    const float* __restrict__ kin, const float* __restrict__ vin,
    const short* __restrict__ pjh, const short* __restrict__ pjl,
    float* __restrict__ ctx_part, float* __restrict__ ksum_part,
    float koff, float diagc){
  extern __shared__ char smem[];
  char* sph = smem;                     // 40960
  char* spl = smem + 40960;             // 40960
  char* skh = smem + 81920;             // 40960 (kp), overlaid by ex[] at end
  float* ex = (float*)(smem + 81920);
  const int tid = threadIdx.x;
  const int w = tid >> 6, lane = tid & 63, g = lane >> 4, q = lane & 15;
  const int bid = blockIdx.x;
  const int head = bid & 31, chunk = bid >> 5;
  for(int i = tid; i < 2560; i += 1024){
    int f = i >> 3;
    int byt = (f*128 + (i & 7)*16) ^ ((f & 7) << 4);
    s16x8 vh8 = {0,0,0,0,0,0,0,0}, vl8 = {0,0,0,0,0,0,0,0};
    if(f < 288){
      vh8 = ((const s16x8*)pjh)[i];
      vl8 = ((const s16x8*)pjl)[i];
    }
    *(s16x8*)(sph + byt) = vh8;
    *(s16x8*)(spl + byt) = vl8;
  }
  const int mtp = w & 3, fqp = w >> 2;
  const int et  = w & 3, fqc = w >> 2;
  f32x4 acc[5];
  #pragma unroll
  for(int a=0;a<5;++a){ f32x4 z = {0.f,0.f,0.f,0.f}; acc[a] = z; }
  float ksacc[5] = {0.f,0.f,0.f,0.f,0.f};
  const float* kbase = kin + (size_t)head*8192*64;
  const float* vbase = vin + (size_t)head*8192*64;
  float4 xa0, xb0, xa1, xb1;
  {
    const float* rp = kbase + (size_t)(chunk*1024 + mtp*16 + q)*64;
    xa0 = *(const float4*)(rp + g*8);       xb0 = *(const float4*)(rp + g*8 + 4);
    xa1 = *(const float4*)(rp + 32 + g*8);  xb1 = *(const float4*)(rp + 32 + g*8 + 4);
  }
  __syncthreads();
  #pragma unroll 1
  for(int it = 0; it < 16; ++it){
    const int nb = chunk*1024 + it*64;
    s16x8 xh[2], xl[2];
    float diag;
    {
      float v0[8] = {xa0.x,xa0.y,xa0.z,xa0.w,xb0.x,xb0.y,xb0.z,xb0.w};
      float v1[8] = {xa1.x,xa1.y,xa1.z,xa1.w,xb1.x,xb1.y,xb1.z,xb1.w};
      float ss = 0.f;
      #pragma unroll
      for(int j=0;j<8;++j){ ss += v0[j]*v0[j]; ss += v1[j]*v1[j]; }
      cvt_hl8(v0, xh[0], xl[0]);
      cvt_hl8(v1, xh[1], xl[1]);
      ss += __shfl_xor(ss, 16); ss += __shfl_xor(ss, 32);
      diag = ss * diagc;
    }
    float dro[4];
    #pragma unroll
    for(int i=0;i<4;++i) dro[i] = __shfl(diag, 4*g + i) - koff;
    s16x8 vh[2], vl[2];
    {
      const int e = et*16 + q;
      #pragma unroll
      for(int ks=0; ks<2; ++ks){
        float vv[8];
        #pragma unroll
        for(int i2=0;i2<8;++i2) vv[i2] = vbase[(size_t)(nb + ks*32 + 8*g + i2)*64 + e];
        cvt_hl8(vv, vh[ks], vl[ks]);
      }
    }
    f32x4 S[5];
    #pragma unroll
    for(int t=0;t<5;++t){ f32x4 z = {0.f,0.f,0.f,0.f}; S[t] = z; }
    #pragma unroll
    for(int t=0; t<5; ++t){
      const int f = (fqp*5 + t)*16 + q;
      #pragma unroll
      for(int ks=0; ks<2; ++ks){
        int byt = (f*128 + ks*64 + g*16) ^ ((f & 7) << 4);
        s16x8 bph = *(const s16x8*)(sph + byt);
        s16x8 bpl = *(const s16x8*)(spl + byt);
        S[t] = MFMA16(xh[ks], bph, S[t]);
        S[t] = MFMA16(xl[ks], bph, S[t]);
        S[t] = MFMA16(xh[ks], bpl, S[t]);
      }
    }
    #pragma unroll
    for(int t=0; t<5; ++t){
      const int f = (fqp*5 + t)*16 + q;
      const bool live = (f < 266);
      float p[4];
      #pragma unroll
      for(int i=0;i<4;++i){
        float e2 = exp2_fast(S[t][i] - dro[i]);
        p[i] = live ? e2 : 0.f;
      }
      ksacc[t] += p[0]+p[1]+p[2]+p[3];
      uint2 hv;
      hv.x = (unsigned)bf16rne(p[0]) | ((unsigned)bf16rne(p[1]) << 16);
      hv.y = (unsigned)bf16rne(p[2]) | ((unsigned)bf16rne(p[3]) << 16);
      int byt = (f*128 + (mtp*16 + 4*g)*2) ^ ((f & 7) << 4);
      *(uint2*)(skh + byt) = hv;
    }
    {
      const int itn = (it + 1) & 15;
      const float* rp = kbase + (size_t)(chunk*1024 + itn*64 + mtp*16 + q)*64;
      xa0 = *(const float4*)(rp + g*8);       xb0 = *(const float4*)(rp + g*8 + 4);
      xa1 = *(const float4*)(rp + 32 + g*8);  xb1 = *(const float4*)(rp + 32 + g*8 + 4);
    }
    __syncthreads();   // kp ready
    #pragma unroll
    for(int fm=0; fm<5; ++fm){
      const int fg = (fqc*5 + fm)*16 + q;
      #pragma unroll
      for(int ks=0; ks<2; ++ks){
        int byt = (fg*128 + ks*64 + g*16) ^ ((fg & 7) << 4);
        s16x8 kf = *(const s16x8*)(skh + byt);
        acc[fm] = MFMA16(kf, vh[ks], acc[fm]);
        acc[fm] = MFMA16(kf, vl[ks], acc[fm]);
      }
    }
    __syncthreads();   // kp LDS reusable
  }
  {
    float* cp = ctx_part + (size_t)bid*288*64;
    #pragma unroll
    for(int fm=0; fm<5; ++fm){
      const int gt = fqc*5 + fm;
      if(gt < 18){
        #pragma unroll
        for(int i=0;i<4;++i){
          int f = gt*16 + 4*g + i;
          cp[f*64 + et*16 + q] = acc[fm][i];
        }
      }
    }
  }
  #pragma unroll
  for(int t=0; t<5; ++t){
    float s = ksacc[t];
    s += __shfl_xor(s, 16); s += __shfl_xor(s, 32);
    if(g == 0) ex[mtp*320 + (fqp*5 + t)*16 + q] = s;
  }
  __syncthreads();
  for(int i = tid; i < 288; i += 1024)
    ksum_part[(size_t)bid*288 + i] = ex[i] + ex[320+i] + ex[640+i] + ex[960+i];
}

// ---------------- reduce: sum 8 chunk partials -> ctx hi (e-major) + ksum ----------------
__global__ void fa21_reduce(const float* __restrict__ ctx_part, const float* __restrict__ ksum_part,
                            short* __restrict__ cth, float* __restrict__ ksum){
  int h = blockIdx.x >> 3, sl = blockIdx.x & 7, tid = threadIdx.x;
  for(int j = tid; j < 288*8; j += 256){
    int idx = sl*288*8 + j;
    float s = 0.f;
    #pragma unroll
    for(int c=0;c<8;++c) s += ctx_part[(size_t)(h + 32*c)*288*64 + idx];
    int f = idx >> 6, e = idx & 63;
    cth[(size_t)h*64*288 + e*288 + f] = (short)bf16rne(s);
  }
  if(sl == 0){
    for(int idx = tid; idx < 288; idx += 256){
      float s = 0.f;
      #pragma unroll
      for(int c=0;c<8;++c) s += ksum_part[(size_t)(h + 32*c)*288 + idx];
      ksum[h*288 + idx] = s;
    }
  }
}

// ---------------- phase 2: qp -> out (swapped-operand phi) ----------------
// grid 256, 1024 thr, 16 iters x 64 rows. wave = (mt4 = w&3, fq = w>>2).
// phi: S^T = mfma(A=proj, B=X) -> lane holds S[f=(fq*5+t)*16+4g+i][n=q].
__global__ __launch_bounds__(1024,1) void fa21_p2(
    const float* __restrict__ qin,
    const short* __restrict__ pjh, const short* __restrict__ pjl,
    const short* __restrict__ cth,
    const float* __restrict__ ksum, float* __restrict__ outp,
    float qoff, float qeps, float diagc){
  extern __shared__ char smem[];
  char* spl = smem;                        // 40960 projL swz
  char* sct = smem + 40960;                // 41984 ctxH [64 e][656B]
  char* sqp = smem + 82944;                // 41984 qp-hi [64 n][656B]
  float* rmx = (float*)(smem + 124928);    // [4 fq][64 n]
  float* dnb = (float*)(smem + 125952);    // [4 fq][64 n]
  float* sks = (float*)(smem + 126976);    // [320]
  const int tid = threadIdx.x;
  const int w = tid >> 6, lane = tid & 63, g = lane >> 4, q = lane & 15;
  const int bid = blockIdx.x;
  const int head = bid & 31, chunk = bid >> 5;
  const int mt4 = w & 3, fq = w >> 2;
  for(int i = tid; i < 2560; i += 1024){
    int f = i >> 3;
    int byt = (f*128 + (i & 7)*16) ^ ((f & 7) << 4);
    s16x8 vl8 = {0,0,0,0,0,0,0,0};
    if(f < 288) vl8 = ((const s16x8*)pjl)[i];
    *(s16x8*)(spl + byt) = vl8;
  }
  {
    const short* cb = cth + (size_t)head*18432;
    for(int i = tid; i < 2560; i += 1024){
      int e = i / 40, j = i - e*40;
      int f0 = j*8;
      s16x8 v8 = {0,0,0,0,0,0,0,0};
      if(f0 < 288) v8 = *(const s16x8*)(cb + e*288 + f0);
      *(s16x8*)(sct + e*656 + f0*2) = v8;
    }
  }
  for(int i = tid; i < 320; i += 1024) sks[i] = (i < 288) ? ksum[head*288 + i] : 0.f;
  s16x8 aph[5][2];
  #pragma unroll
  for(int t=0; t<5; ++t){
    const int f = (fq*5 + t)*16 + q;
    #pragma unroll
    for(int ks=0; ks<2; ++ks){
      s16x8 v8 = {0,0,0,0,0,0,0,0};
      if(f < 288) v8 = *(const s16x8*)(pjh + f*64 + ks*32 + g*8);
      aph[t][ks] = v8;
    }
  }
  const float* qbase = qin + (size_t)head*8192*64;
  float* obase = outp + (size_t)head*8192*64;
  __syncthreads();
  #pragma unroll 1
  for(int it=0; it<16; ++it){
    const int nb = chunk*1024 + it*64;
    s16x8 xh[2], xl[2];
    float diag;
    {
      const float* rp = qbase + (size_t)(nb + mt4*16 + q)*64;
      float ss = 0.f;
      #pragma unroll
      for(int ks=0; ks<2; ++ks){
        float4 a = *(const float4*)(rp + ks*32 + g*8);
        float4 b = *(const float4*)(rp + ks*32 + g*8 + 4);
        float vv[8] = {a.x,a.y,a.z,a.w,b.x,b.y,b.z,b.w};
        #pragma unroll
        for(int j=0;j<8;++j) ss += vv[j]*vv[j];
        cvt_hl8(vv, xh[ks], xl[ks]);
      }
      ss += __shfl_xor(ss, 16); ss += __shfl_xor(ss, 32);
      diag = ss * diagc;
    }
    f32x4 S[5];
    #pragma unroll
    for(int t=0;t<5;++t){ f32x4 z = {0.f,0.f,0.f,0.f}; S[t] = z; }
    #pragma unroll
    for(int t=0; t<5; ++t){
      const int f = (fq*5 + t)*16 + q;
      #pragma unroll
      for(int ks=0; ks<2; ++ks){
        int byt = (f*128 + ks*64 + g*16) ^ ((f & 7) << 4);
        s16x8 bpl = *(const s16x8*)(spl + byt);
        S[t] = MFMA16(aph[t][ks], xh[ks], S[t]);
        S[t] = MFMA16(aph[t][ks], xl[ks], S[t]);
        S[t] = MFMA16(bpl, xh[ks], S[t]);
      }
    }
    float m = -3e38f;
    #pragma unroll
    for(int t=0; t<5; ++t){
      const int fb = (fq*5 + t)*16 + 4*g;
      #pragma unroll
      for(int i=0;i<4;++i){
        float v = (fb + i < 266) ? S[t][i] : -3e38f;
        m = fmaxf(m, v);
      }
    }
    m = fmaxf(m, __shfl_xor(m, 16));
    m = fmaxf(m, __shfl_xor(m, 32));
    if(lane < 16) rmx[fq*64 + mt4*16 + q] = m;
    __syncthreads();  // bar1: rowmax partials ready
    const int nrow = mt4*16 + q;
    float rm = fmaxf(fmaxf(rmx[nrow], rmx[64 + nrow]),
                     fmaxf(rmx[128 + nrow], rmx[192 + nrow]));
    const float dro = diag + rm - qoff;
    float dnp = 0.f;
    #pragma unroll
    for(int t=0; t<5; ++t){
      const int fb = (fq*5 + t)*16 + 4*g;
      f32x4 kv = *(const f32x4*)(sks + fb);
      float pe[4];
      #pragma unroll
      for(int i=0;i<4;++i){
        float e2 = exp2_fast(S[t][i] - dro) + qeps;
        pe[i] = (fb + i < 266) ? e2 : 0.f;
        dnp += pe[i] * kv[i];
      }
      uint2 hv;
      hv.x = (unsigned)bf16rne(pe[0]) | ((unsigned)bf16rne(pe[1]) << 16);
      hv.y = (unsigned)bf16rne(pe[2]) | ((unsigned)bf16rne(pe[3]) << 16);
      *(uint2*)(sqp + nrow*656 + fb*2) = hv;
    }
    dnp += __shfl_xor(dnp, 16);
    dnp += __shfl_xor(dnp, 32);
    if(lane < 16) dnb[fq*64 + nrow] = dnp;
    __syncthreads();  // bar2: qp + denom ready
    f32x4 dsum;
    {
      f32x4 d0 = *(const f32x4*)(dnb +       mt4*16 + 4*g);
      f32x4 d1 = *(const f32x4*)(dnb +  64 + mt4*16 + 4*g);
      f32x4 d2 = *(const f32x4*)(dnb + 128 + mt4*16 + 4*g);
      f32x4 d3 = *(const f32x4*)(dnb + 192 + mt4*16 + 4*g);
      #pragma unroll
      for(int i=0;i<4;++i) dsum[i] = d0[i] + d1[i] + d2[i] + d3[i];
    }
    f32x4 oacc = {0.f,0.f,0.f,0.f};
    #pragma unroll
    for(int ks=0; ks<10; ++ks){
      s16x8 ah = *(const s16x8*)(sqp + (mt4*16 + q)*656 + ks*64 + g*16);
      s16x8 ch = *(const s16x8*)(sct + (fq*16 + q)*656 + ks*64 + g*16);
      oacc = MFMA16(ah, ch, oacc);
    }
    #pragma unroll
    for(int i=0;i<4;++i){
      int row = mt4*16 + 4*g + i;
      obase[(size_t)(nb + row)*64 + fq*16 + q] = oacc[i] / (dsum[i] + 1e-8f);
    }
  }
}

extern "C" void kernel_launch(void* const* d_in, const int* in_sizes, int n_in,
                              void* d_out, int out_size, void* d_ws, size_t ws_size,
                              hipStream_t stream){
  const float* q    = (const float*)d_in[0];
  const float* k    = (const float*)d_in[1];
  const float* v    = (const float*)d_in[2];
  const float* proj = (const float*)d_in[3];
  float* out = (float*)d_out;
  char* ws = (char*)d_ws;
  short* wproj_h = (short*)(ws);
  short* wproj_l = (short*)(ws + 36864);
  float* wctx    = (float*)(ws + 73728);
  float* wksump  = (float*)(ws + 18948096);          // 73728 + 256*288*64*4
  short* wct_h   = (short*)(ws + 19243008);          // + 256*288*4
  float* wksum   = (float*)(ws + 20422656);          // + 32*64*288*2

  const double LOG2E = 1.4426950408889634;
  const double ln_ratio = -0.5*log(266.0);
  float pscale = (float)(pow(64.0, -0.25) * LOG2E);
  float diagc  = (float)(0.0625 * LOG2E);
  float koff   = (float)((1e-4 + ln_ratio) * LOG2E);
  float qoff   = (float)(ln_ratio * LOG2E);
  float qeps   = (float)(1e-4 / sqrt(266.0));

  hipFuncSetAttribute((const void*)fa21_p1, hipFuncAttributeMaxDynamicSharedMemorySize, 122880);
  hipFuncSetAttribute((const void*)fa21_p2, hipFuncAttributeMaxDynamicSharedMemorySize, 128256);

  fa21_prep<<<72, 256, 0, stream>>>(proj, wproj_h, wproj_l, pscale);
  fa21_p1<<<256, 1024, 122880, stream>>>(k, v, wproj_h, wproj_l, wctx, wksump, koff, diagc);
  fa21_reduce<<<256, 256, 0, stream>>>(wctx, wksump, wct_h, wksum);
  fa21_p2<<<256, 1024, 128256, stream>>>(q, wproj_h, wproj_l, wct_h, wksum, out,
                                         qoff, qeps, diagc);
}

// Round 11
// 181.156 us; speedup vs baseline: 3.9586x; 1.1191x over previous
//
#include <hip/hip_runtime.h>
#include <hip/hip_bf16.h>
#include <math.h>

// FAVOR+ (Performer) non-causal linear attention, b=4 h=8 n=8192 d=64 f=266.
// Round 11: drop proj-lo product everywhere (phi 2-product: xh*ph + xl*ph;
// proj quantized to bf16-hi once) -> p1 MFMA 25->20, p2 phi has zero LDS reads.
// p1 kp double-buffered -> 1 barrier/iter (freed proj-lo LDS = 2nd buffer).
// p2 drops spl staging. Numerics: +~0.3-1% per-feature phi error, mostly
// cancels through normalization; predicted absmax ~0.025 (threshold 0.05).

typedef __attribute__((ext_vector_type(8))) short s16x8;
typedef __attribute__((ext_vector_type(4))) float f32x4;

#define MFMA16(a,b,c) __builtin_amdgcn_mfma_f32_16x16x32_bf16((a),(b),(c),0,0,0)

__device__ __forceinline__ unsigned short bf16rne(float x){
  union { __hip_bfloat16 b; unsigned short u; } cv;
  cv.b = __float2bfloat16(x);
  return cv.u;
}
__device__ __forceinline__ float bf16tof(unsigned short h){
  return __uint_as_float(((unsigned)h) << 16);
}
__device__ __forceinline__ float exp2_fast(float x){
#if __has_builtin(__builtin_amdgcn_exp2f)
  return __builtin_amdgcn_exp2f(x);
#else
  float r; asm("v_exp_f32 %0, %1" : "=v"(r) : "v"(x)); return r;
#endif
}
__device__ __forceinline__ void cvt_hl8(const float v[8], s16x8& h, s16x8& l){
  #pragma unroll
  for(int j=0;j<8;++j){
    unsigned short hh = bf16rne(v[j]);
    h[j] = (short)hh;
    l[j] = (short)bf16rne(v[j] - bf16tof(hh));
  }
}

// ---------------- prep: scaled/padded proj hi (288 rows) ----------------
__global__ void fa21_prep(const float* __restrict__ proj, short* __restrict__ ph,
                          float pscale){
  int idx = blockIdx.x*256 + threadIdx.x;
  if(idx >= 288*64) return;
  int f = idx >> 6, dc = idx & 63;
  float v = (f < 266) ? proj[f*64 + dc]*pscale : 0.f;
  ph[idx] = (short)bf16rne(v);
}

// ---------------- phase 1: kp -> context partials + ksum partials ----------------
// grid 256 = 32 heads x 8 chunks, 1024 thr (16 waves), 16 iters x 64 rows.
// phi role: (mtp = w&3 row-tile, fqp = w>>2 f-quarter of 5 tiles), 2-product.
// ctx role: (et = w&3, fqc = w>>2), 2-product (kp-hi x V-hi/lo).
// LDS: projH [320][64] swz 40960 + kp dbuf 2x40960 = 122880. ONE barrier/iter.
__global__ __launch_bounds__(1024,1) void fa21_p1(
    const float* __restrict__ kin, const float* __restrict__ vin,
    const short* __restrict__ pjh,
    float* __restrict__ ctx_part, float* __restrict__ ksum_part,
    float koff, float diagc){
  extern __shared__ char smem[];
  char* sph = smem;                     // 40960 (overlaid by ex[] in epilogue)
  char* skh = smem + 40960;             // 2 x 40960 kp double-buffer
  float* ex = (float*)smem;
  const int tid = threadIdx.x;
  const int w = tid >> 6, lane = tid & 63, g = lane >> 4, q = lane & 15;
  const int bid = blockIdx.x;
  const int head = bid & 31, chunk = bid >> 5;
  for(int i = tid; i < 2560; i += 1024){
    int f = i >> 3;
    int byt = (f*128 + (i & 7)*16) ^ ((f & 7) << 4);
    s16x8 vh8 = {0,0,0,0,0,0,0,0};
    if(f < 288) vh8 = ((const s16x8*)pjh)[i];
    *(s16x8*)(sph + byt) = vh8;
  }
  const int mtp = w & 3, fqp = w >> 2;
  const int et  = w & 3, fqc = w >> 2;
  f32x4 acc[5];
  #pragma unroll
  for(int a=0;a<5;++a){ f32x4 z = {0.f,0.f,0.f,0.f}; acc[a] = z; }
  float ksacc[5] = {0.f,0.f,0.f,0.f,0.f};
  const float* kbase = kin + (size_t)head*8192*64;
  const float* vbase = vin + (size_t)head*8192*64;
  float4 xa0, xb0, xa1, xb1;
  {
    const float* rp = kbase + (size_t)(chunk*1024 + mtp*16 + q)*64;
    xa0 = *(const float4*)(rp + g*8);       xb0 = *(const float4*)(rp + g*8 + 4);
    xa1 = *(const float4*)(rp + 32 + g*8);  xb1 = *(const float4*)(rp + 32 + g*8 + 4);
  }
  __syncthreads();
  #pragma unroll 1
  for(int it = 0; it < 16; ++it){
    const int nb = chunk*1024 + it*64;
    char* kcur = skh + (it & 1)*40960;
    s16x8 xh[2], xl[2];
    float diag;
    {
      float v0[8] = {xa0.x,xa0.y,xa0.z,xa0.w,xb0.x,xb0.y,xb0.z,xb0.w};
      float v1[8] = {xa1.x,xa1.y,xa1.z,xa1.w,xb1.x,xb1.y,xb1.z,xb1.w};
      float ss = 0.f;
      #pragma unroll
      for(int j=0;j<8;++j){ ss += v0[j]*v0[j]; ss += v1[j]*v1[j]; }
      cvt_hl8(v0, xh[0], xl[0]);
      cvt_hl8(v1, xh[1], xl[1]);
      ss += __shfl_xor(ss, 16); ss += __shfl_xor(ss, 32);
      diag = ss * diagc;
    }
    float dro[4];
    #pragma unroll
    for(int i=0;i<4;++i) dro[i] = __shfl(diag, 4*g + i) - koff;
    // V B-frags (hi/lo), issued early so latency hides under phi
    s16x8 vh[2], vl[2];
    {
      const int e = et*16 + q;
      #pragma unroll
      for(int ks=0; ks<2; ++ks){
        float vv[8];
        #pragma unroll
        for(int i2=0;i2<8;++i2) vv[i2] = vbase[(size_t)(nb + ks*32 + 8*g + i2)*64 + e];
        cvt_hl8(vv, vh[ks], vl[ks]);
      }
    }
    // phi: 2-product (xh*ph + xl*ph)
    f32x4 S[5];
    #pragma unroll
    for(int t=0;t<5;++t){ f32x4 z = {0.f,0.f,0.f,0.f}; S[t] = z; }
    #pragma unroll
    for(int t=0; t<5; ++t){
      const int f = (fqp*5 + t)*16 + q;
      #pragma unroll
      for(int ks=0; ks<2; ++ks){
        int byt = (f*128 + ks*64 + g*16) ^ ((f & 7) << 4);
        s16x8 bph = *(const s16x8*)(sph + byt);
        S[t] = MFMA16(xh[ks], bph, S[t]);
        S[t] = MFMA16(xl[ks], bph, S[t]);
      }
    }
    // kp = exp2(S - diag + koff), mask, ksum, pack hi -> kp dbuf
    #pragma unroll
    for(int t=0; t<5; ++t){
      const int f = (fqp*5 + t)*16 + q;
      const bool live = (f < 266);
      float p[4];
      #pragma unroll
      for(int i=0;i<4;++i){
        float e2 = exp2_fast(S[t][i] - dro[i]);
        p[i] = live ? e2 : 0.f;
      }
      ksacc[t] += p[0]+p[1]+p[2]+p[3];
      uint2 hv;
      hv.x = (unsigned)bf16rne(p[0]) | ((unsigned)bf16rne(p[1]) << 16);
      hv.y = (unsigned)bf16rne(p[2]) | ((unsigned)bf16rne(p[3]) << 16);
      int byt = (f*128 + (mtp*16 + 4*g)*2) ^ ((f & 7) << 4);
      *(uint2*)(kcur + byt) = hv;
    }
    // prefetch X for next iter
    {
      const int itn = (it + 1) & 15;
      const float* rp = kbase + (size_t)(chunk*1024 + itn*64 + mtp*16 + q)*64;
      xa0 = *(const float4*)(rp + g*8);       xb0 = *(const float4*)(rp + g*8 + 4);
      xa1 = *(const float4*)(rp + 32 + g*8);  xb1 = *(const float4*)(rp + 32 + g*8 + 4);
    }
    __syncthreads();   // kp[cur] ready (single barrier per iter; dbuf)
    // context += kpT * V (2-product)
    #pragma unroll
    for(int fm=0; fm<5; ++fm){
      const int fg = (fqc*5 + fm)*16 + q;
      #pragma unroll
      for(int ks=0; ks<2; ++ks){
        int byt = (fg*128 + ks*64 + g*16) ^ ((fg & 7) << 4);
        s16x8 kf = *(const s16x8*)(kcur + byt);
        acc[fm] = MFMA16(kf, vh[ks], acc[fm]);
        acc[fm] = MFMA16(kf, vl[ks], acc[fm]);
      }
    }
  }
  {
    float* cp = ctx_part + (size_t)bid*288*64;
    #pragma unroll
    for(int fm=0; fm<5; ++fm){
      const int gt = fqc*5 + fm;
      if(gt < 18){
        #pragma unroll
        for(int i=0;i<4;++i){
          int f = gt*16 + 4*g + i;
          cp[f*64 + et*16 + q] = acc[fm][i];
        }
      }
    }
  }
  __syncthreads();   // all phi reads of sph done; reuse as ex[]
  #pragma unroll
  for(int t=0; t<5; ++t){
    float s = ksacc[t];
    s += __shfl_xor(s, 16); s += __shfl_xor(s, 32);
    if(g == 0) ex[mtp*320 + (fqp*5 + t)*16 + q] = s;
  }
  __syncthreads();
  for(int i = tid; i < 288; i += 1024)
    ksum_part[(size_t)bid*288 + i] = ex[i] + ex[320+i] + ex[640+i] + ex[960+i];
}

// ---------------- reduce: sum 8 chunk partials -> ctx hi (e-major) + ksum ----------------
__global__ void fa21_reduce(const float* __restrict__ ctx_part, const float* __restrict__ ksum_part,
                            short* __restrict__ cth, float* __restrict__ ksum){
  int h = blockIdx.x >> 3, sl = blockIdx.x & 7, tid = threadIdx.x;
  for(int j = tid; j < 288*8; j += 256){
    int idx = sl*288*8 + j;
    float s = 0.f;
    #pragma unroll
    for(int c=0;c<8;++c) s += ctx_part[(size_t)(h + 32*c)*288*64 + idx];
    int f = idx >> 6, e = idx & 63;
    cth[(size_t)h*64*288 + e*288 + f] = (short)bf16rne(s);
  }
  if(sl == 0){
    for(int idx = tid; idx < 288; idx += 256){
      float s = 0.f;
      #pragma unroll
      for(int c=0;c<8;++c) s += ksum_part[(size_t)(h + 32*c)*288 + idx];
      ksum[h*288 + idx] = s;
    }
  }
}

// ---------------- phase 2: qp -> out (swapped-operand phi, reg-only phi) ----------------
// grid 256, 1024 thr, 16 iters x 64 rows. wave = (mt4 = w&3, fq = w>>2).
// phi: S^T = mfma(A=projH regs, B=X hi/lo) -> lane holds S[f=(fq*5+t)*16+4g+i][n=q].
// LDS: ctxH [64][656] 41984 + qp [64][656] 41984 + rmx 1024 + dnb 1024 + ksum 1280.
__global__ __launch_bounds__(1024,1) void fa21_p2(
    const float* __restrict__ qin,
    const short* __restrict__ pjh,
    const short* __restrict__ cth,
    const float* __restrict__ ksum, float* __restrict__ outp,
    float qoff, float qeps, float diagc){
  extern __shared__ char smem[];
  char* sct = smem;                        // 41984 ctxH [64 e][656B]
  char* sqp = smem + 41984;                // 41984 qp-hi [64 n][656B]
  float* rmx = (float*)(smem + 83968);     // [4 fq][64 n]
  float* dnb = (float*)(smem + 84992);     // [4 fq][64 n]
  float* sks = (float*)(smem + 86016);     // [320]
  const int tid = threadIdx.x;
  const int w = tid >> 6, lane = tid & 63, g = lane >> 4, q = lane & 15;
  const int bid = blockIdx.x;
  const int head = bid & 31, chunk = bid >> 5;
  const int mt4 = w & 3, fq = w >> 2;
  {
    const short* cb = cth + (size_t)head*18432;
    for(int i = tid; i < 2560; i += 1024){
      int e = i / 40, j = i - e*40;
      int f0 = j*8;
      s16x8 v8 = {0,0,0,0,0,0,0,0};
      if(f0 < 288) v8 = *(const s16x8*)(cb + e*288 + f0);
      *(s16x8*)(sct + e*656 + f0*2) = v8;
    }
  }
  for(int i = tid; i < 320; i += 1024) sks[i] = (i < 288) ? ksum[head*288 + i] : 0.f;
  s16x8 aph[5][2];
  #pragma unroll
  for(int t=0; t<5; ++t){
    const int f = (fq*5 + t)*16 + q;
    #pragma unroll
    for(int ks=0; ks<2; ++ks){
      s16x8 v8 = {0,0,0,0,0,0,0,0};
      if(f < 288) v8 = *(const s16x8*)(pjh + f*64 + ks*32 + g*8);
      aph[t][ks] = v8;
    }
  }
  const float* qbase = qin + (size_t)head*8192*64;
  float* obase = outp + (size_t)head*8192*64;
  __syncthreads();
  #pragma unroll 1
  for(int it=0; it<16; ++it){
    const int nb = chunk*1024 + it*64;
    s16x8 xh[2], xl[2];
    float diag;
    {
      const float* rp = qbase + (size_t)(nb + mt4*16 + q)*64;
      float ss = 0.f;
      #pragma unroll
      for(int ks=0; ks<2; ++ks){
        float4 a = *(const float4*)(rp + ks*32 + g*8);
        float4 b = *(const float4*)(rp + ks*32 + g*8 + 4);
        float vv[8] = {a.x,a.y,a.z,a.w,b.x,b.y,b.z,b.w};
        #pragma unroll
        for(int j=0;j<8;++j) ss += vv[j]*vv[j];
        cvt_hl8(vv, xh[ks], xl[ks]);
      }
      ss += __shfl_xor(ss, 16); ss += __shfl_xor(ss, 32);
      diag = ss * diagc;
    }
    // phi swapped, 2-product, register-only operands
    f32x4 S[5];
    #pragma unroll
    for(int t=0;t<5;++t){ f32x4 z = {0.f,0.f,0.f,0.f}; S[t] = z; }
    #pragma unroll
    for(int t=0; t<5; ++t){
      #pragma unroll
      for(int ks=0; ks<2; ++ks){
        S[t] = MFMA16(aph[t][ks], xh[ks], S[t]);
        S[t] = MFMA16(aph[t][ks], xl[ks], S[t]);
      }
    }
    float m = -3e38f;
    #pragma unroll
    for(int t=0; t<5; ++t){
      const int fb = (fq*5 + t)*16 + 4*g;
      #pragma unroll
      for(int i=0;i<4;++i){
        float v = (fb + i < 266) ? S[t][i] : -3e38f;
        m = fmaxf(m, v);
      }
    }
    m = fmaxf(m, __shfl_xor(m, 16));
    m = fmaxf(m, __shfl_xor(m, 32));
    if(lane < 16) rmx[fq*64 + mt4*16 + q] = m;
    __syncthreads();  // bar1: rowmax partials ready
    const int nrow = mt4*16 + q;
    float rm = fmaxf(fmaxf(rmx[nrow], rmx[64 + nrow]),
                     fmaxf(rmx[128 + nrow], rmx[192 + nrow]));
    const float dro = diag + rm - qoff;
    float dnp = 0.f;
    #pragma unroll
    for(int t=0; t<5; ++t){
      const int fb = (fq*5 + t)*16 + 4*g;
      f32x4 kv = *(const f32x4*)(sks + fb);
      float pe[4];
      #pragma unroll
      for(int i=0;i<4;++i){
        float e2 = exp2_fast(S[t][i] - dro) + qeps;
        pe[i] = (fb + i < 266) ? e2 : 0.f;
        dnp += pe[i] * kv[i];
      }
      uint2 hv;
      hv.x = (unsigned)bf16rne(pe[0]) | ((unsigned)bf16rne(pe[1]) << 16);
      hv.y = (unsigned)bf16rne(pe[2]) | ((unsigned)bf16rne(pe[3]) << 16);
      *(uint2*)(sqp + nrow*656 + fb*2) = hv;
    }
    dnp += __shfl_xor(dnp, 16);
    dnp += __shfl_xor(dnp, 32);
    if(lane < 16) dnb[fq*64 + nrow] = dnp;
    __syncthreads();  // bar2: qp + denom ready
    f32x4 dsum;
    {
      f32x4 d0 = *(const f32x4*)(dnb +       mt4*16 + 4*g);
      f32x4 d1 = *(const f32x4*)(dnb +  64 + mt4*16 + 4*g);
      f32x4 d2 = *(const f32x4*)(dnb + 128 + mt4*16 + 4*g);
      f32x4 d3 = *(const f32x4*)(dnb + 192 + mt4*16 + 4*g);
      #pragma unroll
      for(int i=0;i<4;++i) dsum[i] = d0[i] + d1[i] + d2[i] + d3[i];
    }
    f32x4 oacc = {0.f,0.f,0.f,0.f};
    #pragma unroll
    for(int ks=0; ks<10; ++ks){
      s16x8 ah = *(const s16x8*)(sqp + (mt4*16 + q)*656 + ks*64 + g*16);
      s16x8 ch = *(const s16x8*)(sct + (fq*16 + q)*656 + ks*64 + g*16);
      oacc = MFMA16(ah, ch, oacc);
    }
    #pragma unroll
    for(int i=0;i<4;++i){
      int row = mt4*16 + 4*g + i;
      obase[(size_t)(nb + row)*64 + fq*16 + q] = oacc[i] / (dsum[i] + 1e-8f);
    }
  }
}

extern "C" void kernel_launch(void* const* d_in, const int* in_sizes, int n_in,
                              void* d_out, int out_size, void* d_ws, size_t ws_size,
                              hipStream_t stream){
  const float* q    = (const float*)d_in[0];
  const float* k    = (const float*)d_in[1];
  const float* v    = (const float*)d_in[2];
  const float* proj = (const float*)d_in[3];
  float* out = (float*)d_out;
  char* ws = (char*)d_ws;
  short* wproj_h = (short*)(ws);
  float* wctx    = (float*)(ws + 73728);
  float* wksump  = (float*)(ws + 18948096);          // 73728 + 256*288*64*4
  short* wct_h   = (short*)(ws + 19243008);          // + 256*288*4
  float* wksum   = (float*)(ws + 20422656);          // + 32*64*288*2

  const double LOG2E = 1.4426950408889634;
  const double ln_ratio = -0.5*log(266.0);
  float pscale = (float)(pow(64.0, -0.25) * LOG2E);
  float diagc  = (float)(0.0625 * LOG2E);
  float koff   = (float)((1e-4 + ln_ratio) * LOG2E);
  float qoff   = (float)(ln_ratio * LOG2E);
  float qeps   = (float)(1e-4 / sqrt(266.0));

  hipFuncSetAttribute((const void*)fa21_p1, hipFuncAttributeMaxDynamicSharedMemorySize, 122880);
  hipFuncSetAttribute((const void*)fa21_p2, hipFuncAttributeMaxDynamicSharedMemorySize, 87296);

  fa21_prep<<<72, 256, 0, stream>>>(proj, wproj_h, pscale);
  fa21_p1<<<256, 1024, 122880, stream>>>(k, v, wproj_h, wctx, wksump, koff, diagc);
  fa21_reduce<<<256, 256, 0, stream>>>(wctx, wksump, wct_h, wksum);
  fa21_p2<<<256, 1024, 87296, stream>>>(q, wproj_h, wct_h, wksum, out,
                                        qoff, qeps, diagc);
}

// Round 12
// 174.621 us; speedup vs baseline: 4.1068x; 1.0374x over previous
//
#include <hip/hip_runtime.h>
#include <hip/hip_bf16.h>
#include <math.h>

// FAVOR+ (Performer) non-causal linear attention, b=4 h=8 n=8192 d=64 f=266.
// Round 12: bit-exact VALU diet on round 11. (1) loop-carried pointers +
// immediate offsets replace per-load 64-bit address math (p1 V/X, p2 X/out).
// (2) dead f-tiles (gt>=17, all-pad) skipped via wave-uniform branches.
// (3) p2 drops all qp masking (ctx/ksum already zero for f>=266); one-time
// zero-init of sqp f in [272,288). (4) p2 out-GEMM 10 -> 9 K-tiles.

typedef __attribute__((ext_vector_type(8))) short s16x8;
typedef __attribute__((ext_vector_type(4))) float f32x4;

#define MFMA16(a,b,c) __builtin_amdgcn_mfma_f32_16x16x32_bf16((a),(b),(c),0,0,0)

__device__ __forceinline__ unsigned short bf16rne(float x){
  union { __hip_bfloat16 b; unsigned short u; } cv;
  cv.b = __float2bfloat16(x);
  return cv.u;
}
__device__ __forceinline__ float bf16tof(unsigned short h){
  return __uint_as_float(((unsigned)h) << 16);
}
__device__ __forceinline__ float exp2_fast(float x){
#if __has_builtin(__builtin_amdgcn_exp2f)
  return __builtin_amdgcn_exp2f(x);
#else
  float r; asm("v_exp_f32 %0, %1" : "=v"(r) : "v"(x)); return r;
#endif
}
__device__ __forceinline__ void cvt_hl8(const float v[8], s16x8& h, s16x8& l){
  #pragma unroll
  for(int j=0;j<8;++j){
    unsigned short hh = bf16rne(v[j]);
    h[j] = (short)hh;
    l[j] = (short)bf16rne(v[j] - bf16tof(hh));
  }
}

// ---------------- prep: scaled/padded proj hi (288 rows) ----------------
__global__ void fa21_prep(const float* __restrict__ proj, short* __restrict__ ph,
                          float pscale){
  int idx = blockIdx.x*256 + threadIdx.x;
  if(idx >= 288*64) return;
  int f = idx >> 6, dc = idx & 63;
  float v = (f < 266) ? proj[f*64 + dc]*pscale : 0.f;
  ph[idx] = (short)bf16rne(v);
}

// ---------------- phase 1: kp -> context partials + ksum partials ----------------
// grid 256 = 32 heads x 8 chunks, 1024 thr (16 waves), 16 iters x 64 rows.
// phi role: (mtp = w&3 row-tile, fqp = w>>2 f-quarter), 2-product, gt<=16 only.
// ctx role: (et = w&3, fqc = w>>2), 2-product, gt<=16 only.
// LDS: projH [320][64] swz 40960 + kp dbuf 2x40960 = 122880. ONE barrier/iter.
__global__ __launch_bounds__(1024,1) void fa21_p1(
    const float* __restrict__ kin, const float* __restrict__ vin,
    const short* __restrict__ pjh,
    float* __restrict__ ctx_part, float* __restrict__ ksum_part,
    float koff, float diagc){
  extern __shared__ char smem[];
  char* sph = smem;                     // 40960 (overlaid by ex[] in epilogue)
  char* skh = smem + 40960;             // 2 x 40960 kp double-buffer
  float* ex = (float*)smem;
  const int tid = threadIdx.x;
  const int w = tid >> 6, lane = tid & 63, g = lane >> 4, q = lane & 15;
  const int bid = blockIdx.x;
  const int head = bid & 31, chunk = bid >> 5;
  for(int i = tid; i < 2560; i += 1024){
    int f = i >> 3;
    int byt = (f*128 + (i & 7)*16) ^ ((f & 7) << 4);
    s16x8 vh8 = {0,0,0,0,0,0,0,0};
    if(f < 288) vh8 = ((const s16x8*)pjh)[i];
    *(s16x8*)(sph + byt) = vh8;
  }
  const int mtp = w & 3, fqp = w >> 2;
  const int et  = w & 3, fqc = w >> 2;
  f32x4 acc[5];
  #pragma unroll
  for(int a=0;a<5;++a){ f32x4 z = {0.f,0.f,0.f,0.f}; acc[a] = z; }
  float ksacc[5] = {0.f,0.f,0.f,0.f,0.f};
  const float* kbase = kin + (size_t)head*8192*64;
  const float* vbase = vin + (size_t)head*8192*64;
  // loop-carried pointers (immediate-offset loads inside the loop)
  const float* xp  = kbase + (size_t)(chunk*1024 + mtp*16 + q)*64 + g*8;
  const float* vp  = vbase + (size_t)(chunk*1024 + 8*g)*64 + et*16 + q;
  const float* vp2 = vp + 2048;
  float4 xa0 = *(const float4*)(xp);
  float4 xb0 = *(const float4*)(xp + 4);
  float4 xa1 = *(const float4*)(xp + 32);
  float4 xb1 = *(const float4*)(xp + 36);
  __syncthreads();
  #pragma unroll 1
  for(int it = 0; it < 16; ++it){
    char* kcur = skh + (it & 1)*40960;
    s16x8 xh[2], xl[2];
    float diag;
    {
      float v0[8] = {xa0.x,xa0.y,xa0.z,xa0.w,xb0.x,xb0.y,xb0.z,xb0.w};
      float v1[8] = {xa1.x,xa1.y,xa1.z,xa1.w,xb1.x,xb1.y,xb1.z,xb1.w};
      float ss = 0.f;
      #pragma unroll
      for(int j=0;j<8;++j){ ss += v0[j]*v0[j]; ss += v1[j]*v1[j]; }
      cvt_hl8(v0, xh[0], xl[0]);
      cvt_hl8(v1, xh[1], xl[1]);
      ss += __shfl_xor(ss, 16); ss += __shfl_xor(ss, 32);
      diag = ss * diagc;
    }
    float dro[4];
    #pragma unroll
    for(int i=0;i<4;++i) dro[i] = __shfl(diag, 4*g + i) - koff;
    // V B-frags (hi/lo), immediate-offset loads, issued before phi
    s16x8 vh[2], vl[2];
    {
      float vv[8];
      #pragma unroll
      for(int i2=0;i2<8;++i2) vv[i2] = vp[i2*64];
      cvt_hl8(vv, vh[0], vl[0]);
      #pragma unroll
      for(int i2=0;i2<8;++i2) vv[i2] = vp2[i2*64];
      cvt_hl8(vv, vh[1], vl[1]);
    }
    vp += 4096; vp2 += 4096;
    // phi: 2-product, live tiles only (gt <= 16)
    f32x4 S[5];
    #pragma unroll
    for(int t=0;t<5;++t){ f32x4 z = {0.f,0.f,0.f,0.f}; S[t] = z; }
    #pragma unroll
    for(int t=0; t<5; ++t){
      const int gt = fqp*5 + t;
      if(gt > 16) continue;
      const int f = gt*16 + q;
      #pragma unroll
      for(int ks=0; ks<2; ++ks){
        int byt = (f*128 + ks*64 + g*16) ^ ((f & 7) << 4);
        s16x8 bph = *(const s16x8*)(sph + byt);
        S[t] = MFMA16(xh[ks], bph, S[t]);
        S[t] = MFMA16(xl[ks], bph, S[t]);
      }
    }
    // kp = exp2(S - diag + koff), mask only boundary tile, pack -> kp dbuf
    #pragma unroll
    for(int t=0; t<5; ++t){
      const int gt = fqp*5 + t;
      if(gt > 16) continue;
      const int f = gt*16 + q;
      float p[4];
      #pragma unroll
      for(int i=0;i<4;++i) p[i] = exp2_fast(S[t][i] - dro[i]);
      if(gt == 16){
        #pragma unroll
        for(int i=0;i<4;++i) p[i] = (q < 10) ? p[i] : 0.f;
      }
      ksacc[t] += p[0]+p[1]+p[2]+p[3];
      uint2 hv;
      hv.x = (unsigned)bf16rne(p[0]) | ((unsigned)bf16rne(p[1]) << 16);
      hv.y = (unsigned)bf16rne(p[2]) | ((unsigned)bf16rne(p[3]) << 16);
      int byt = (f*128 + (mtp*16 + 4*g)*2) ^ ((f & 7) << 4);
      *(uint2*)(kcur + byt) = hv;
    }
    // prefetch X for next iter (pointer-carried; skip on last)
    xp += 4096;
    if(it < 15){
      xa0 = *(const float4*)(xp);
      xb0 = *(const float4*)(xp + 4);
      xa1 = *(const float4*)(xp + 32);
      xb1 = *(const float4*)(xp + 36);
    }
    __syncthreads();   // kp[cur] ready (single barrier per iter; dbuf)
    // context += kpT * V (2-product), live tiles only
    #pragma unroll
    for(int fm=0; fm<5; ++fm){
      const int gt = fqc*5 + fm;
      if(gt > 16) continue;
      const int fg = gt*16 + q;
      #pragma unroll
      for(int ks=0; ks<2; ++ks){
        int byt = (fg*128 + ks*64 + g*16) ^ ((fg & 7) << 4);
        s16x8 kf = *(const s16x8*)(kcur + byt);
        acc[fm] = MFMA16(kf, vh[ks], acc[fm]);
        acc[fm] = MFMA16(kf, vl[ks], acc[fm]);
      }
    }
  }
  {
    float* cp = ctx_part + (size_t)bid*288*64;
    #pragma unroll
    for(int fm=0; fm<5; ++fm){
      const int gt = fqc*5 + fm;
      if(gt < 18){
        #pragma unroll
        for(int i=0;i<4;++i){
          int f = gt*16 + 4*g + i;
          cp[f*64 + et*16 + q] = acc[fm][i];
        }
      }
    }
  }
  __syncthreads();   // all phi reads of sph done; reuse as ex[]
  #pragma unroll
  for(int t=0; t<5; ++t){
    float s = ksacc[t];
    s += __shfl_xor(s, 16); s += __shfl_xor(s, 32);
    if(g == 0) ex[mtp*320 + (fqp*5 + t)*16 + q] = s;
  }
  __syncthreads();
  for(int i = tid; i < 288; i += 1024)
    ksum_part[(size_t)bid*288 + i] = ex[i] + ex[320+i] + ex[640+i] + ex[960+i];
}

// ---------------- reduce: sum 8 chunk partials -> ctx hi (e-major) + ksum ----------------
__global__ void fa21_reduce(const float* __restrict__ ctx_part, const float* __restrict__ ksum_part,
                            short* __restrict__ cth, float* __restrict__ ksum){
  int h = blockIdx.x >> 3, sl = blockIdx.x & 7, tid = threadIdx.x;
  for(int j = tid; j < 288*8; j += 256){
    int idx = sl*288*8 + j;
    float s = 0.f;
    #pragma unroll
    for(int c=0;c<8;++c) s += ctx_part[(size_t)(h + 32*c)*288*64 + idx];
    int f = idx >> 6, e = idx & 63;
    cth[(size_t)h*64*288 + e*288 + f] = (short)bf16rne(s);
  }
  if(sl == 0){
    for(int idx = tid; idx < 288; idx += 256){
      float s = 0.f;
      #pragma unroll
      for(int c=0;c<8;++c) s += ksum_part[(size_t)(h + 32*c)*288 + idx];
      ksum[h*288 + idx] = s;
    }
  }
}

// ---------------- phase 2: qp -> out (swapped-operand phi, reg-only phi) ----------------
// grid 256, 1024 thr, 16 iters x 64 rows. wave = (mt4 = w&3, fq = w>>2).
// phi: S^T = mfma(A=projH regs, B=X hi/lo) -> lane holds S[f=gt*16+4g+i][n=q].
// No qp masking (ctx/ksum zero for f>=266). out-GEMM 9 K-tiles (f<288).
__global__ __launch_bounds__(1024,1) void fa21_p2(
    const float* __restrict__ qin,
    const short* __restrict__ pjh,
    const short* __restrict__ cth,
    const float* __restrict__ ksum, float* __restrict__ outp,
    float qoff, float qeps, float diagc){
  extern __shared__ char smem[];
  char* sct = smem;                        // 41984 ctxH [64 e][656B]
  char* sqp = smem + 41984;                // 41984 qp-hi [64 n][656B]
  float* rmx = (float*)(smem + 83968);     // [4 fq][64 n]
  float* dnb = (float*)(smem + 84992);     // [4 fq][64 n]
  float* sks = (float*)(smem + 86016);     // [320]
  const int tid = threadIdx.x;
  const int w = tid >> 6, lane = tid & 63, g = lane >> 4, q = lane & 15;
  const int bid = blockIdx.x;
  const int head = bid & 31, chunk = bid >> 5;
  const int mt4 = w & 3, fq = w >> 2;
  {
    const short* cb = cth + (size_t)head*18432;
    for(int i = tid; i < 2560; i += 1024){
      int e = i / 40, j = i - e*40;
      int f0 = j*8;
      s16x8 v8 = {0,0,0,0,0,0,0,0};
      if(f0 < 288) v8 = *(const s16x8*)(cb + e*288 + f0);
      *(s16x8*)(sct + e*656 + f0*2) = v8;
    }
  }
  // one-time zero of sqp f in [272,288) (read by ks=8, never written per-iter)
  for(int i = tid; i < 64*8; i += 1024){
    int r = i >> 3, dwi = i & 7;
    *(unsigned*)(sqp + r*656 + 544 + dwi*4) = 0u;
  }
  for(int i = tid; i < 320; i += 1024) sks[i] = (i < 288) ? ksum[head*288 + i] : 0.f;
  s16x8 aph[5][2];
  #pragma unroll
  for(int t=0; t<5; ++t){
    const int f = (fq*5 + t)*16 + q;
    #pragma unroll
    for(int ks=0; ks<2; ++ks){
      s16x8 v8 = {0,0,0,0,0,0,0,0};
      if(f < 288) v8 = *(const s16x8*)(pjh + f*64 + ks*32 + g*8);
      aph[t][ks] = v8;
    }
  }
  const float* qbase = qin + (size_t)head*8192*64;
  float* obase = outp + (size_t)head*8192*64;
  // loop-carried pointers
  const float* xp = qbase + (size_t)(chunk*1024 + mt4*16 + q)*64 + g*8;
  float* op = obase + (size_t)(chunk*1024 + mt4*16 + 4*g)*64 + fq*16 + q;
  __syncthreads();
  #pragma unroll 1
  for(int it=0; it<16; ++it){
    s16x8 xh[2], xl[2];
    float diag;
    {
      float4 a0 = *(const float4*)(xp);
      float4 b0 = *(const float4*)(xp + 4);
      float4 a1 = *(const float4*)(xp + 32);
      float4 b1 = *(const float4*)(xp + 36);
      float v0[8] = {a0.x,a0.y,a0.z,a0.w,b0.x,b0.y,b0.z,b0.w};
      float v1[8] = {a1.x,a1.y,a1.z,a1.w,b1.x,b1.y,b1.z,b1.w};
      float ss = 0.f;
      #pragma unroll
      for(int j=0;j<8;++j){ ss += v0[j]*v0[j]; ss += v1[j]*v1[j]; }
      cvt_hl8(v0, xh[0], xl[0]);
      cvt_hl8(v1, xh[1], xl[1]);
      ss += __shfl_xor(ss, 16); ss += __shfl_xor(ss, 32);
      diag = ss * diagc;
    }
    xp += 4096;
    // phi swapped, 2-product, register-only operands, live tiles only
    f32x4 S[5];
    #pragma unroll
    for(int t=0;t<5;++t){ f32x4 z = {0.f,0.f,0.f,0.f}; S[t] = z; }
    #pragma unroll
    for(int t=0; t<5; ++t){
      if(fq*5 + t > 16) continue;
      #pragma unroll
      for(int ks=0; ks<2; ++ks){
        S[t] = MFMA16(aph[t][ks], xh[ks], S[t]);
        S[t] = MFMA16(aph[t][ks], xl[ks], S[t]);
      }
    }
    // rowmax (mask only boundary tile)
    float m = -3e38f;
    #pragma unroll
    for(int t=0; t<5; ++t){
      const int gt = fq*5 + t;
      if(gt > 16) continue;
      if(gt == 16){
        const int fb = gt*16 + 4*g;
        #pragma unroll
        for(int i=0;i<4;++i){
          float v = (fb + i < 266) ? S[t][i] : -3e38f;
          m = fmaxf(m, v);
        }
      } else {
        m = fmaxf(m, fmaxf(fmaxf(S[t][0], S[t][1]), fmaxf(S[t][2], S[t][3])));
      }
    }
    m = fmaxf(m, __shfl_xor(m, 16));
    m = fmaxf(m, __shfl_xor(m, 32));
    if(lane < 16) rmx[fq*64 + mt4*16 + q] = m;
    __syncthreads();  // bar1: rowmax partials ready
    const int nrow = mt4*16 + q;
    float rm = fmaxf(fmaxf(rmx[nrow], rmx[64 + nrow]),
                     fmaxf(rmx[128 + nrow], rmx[192 + nrow]));
    const float dro = diag + rm - qoff;
    // qp = exp2(S - dro) + qeps (NO mask: ctx/ksum zero for f>=266)
    float dnp = 0.f;
    #pragma unroll
    for(int t=0; t<5; ++t){
      const int gt = fq*5 + t;
      if(gt > 16) continue;
      const int fb = gt*16 + 4*g;
      f32x4 kv = *(const f32x4*)(sks + fb);
      float pe[4];
      #pragma unroll
      for(int i=0;i<4;++i){
        pe[i] = exp2_fast(S[t][i] - dro) + qeps;
        dnp += pe[i] * kv[i];
      }
      uint2 hv;
      hv.x = (unsigned)bf16rne(pe[0]) | ((unsigned)bf16rne(pe[1]) << 16);
      hv.y = (unsigned)bf16rne(pe[2]) | ((unsigned)bf16rne(pe[3]) << 16);
      *(uint2*)(sqp + nrow*656 + fb*2) = hv;
    }
    dnp += __shfl_xor(dnp, 16);
    dnp += __shfl_xor(dnp, 32);
    if(lane < 16) dnb[fq*64 + nrow] = dnp;
    __syncthreads();  // bar2: qp + denom ready
    f32x4 dsum;
    {
      f32x4 d0 = *(const f32x4*)(dnb +       mt4*16 + 4*g);
      f32x4 d1 = *(const f32x4*)(dnb +  64 + mt4*16 + 4*g);
      f32x4 d2 = *(const f32x4*)(dnb + 128 + mt4*16 + 4*g);
      f32x4 d3 = *(const f32x4*)(dnb + 192 + mt4*16 + 4*g);
      #pragma unroll
      for(int i=0;i<4;++i) dsum[i] = d0[i] + d1[i] + d2[i] + d3[i];
    }
    f32x4 oacc = {0.f,0.f,0.f,0.f};
    #pragma unroll
    for(int ks=0; ks<9; ++ks){
      s16x8 ah = *(const s16x8*)(sqp + (mt4*16 + q)*656 + ks*64 + g*16);
      s16x8 ch = *(const s16x8*)(sct + (fq*16 + q)*656 + ks*64 + g*16);
      oacc = MFMA16(ah, ch, oacc);
    }
    #pragma unroll
    for(int i=0;i<4;++i){
      op[i*64] = oacc[i] / (dsum[i] + 1e-8f);
    }
    op += 4096;
  }
}

extern "C" void kernel_launch(void* const* d_in, const int* in_sizes, int n_in,
                              void* d_out, int out_size, void* d_ws, size_t ws_size,
                              hipStream_t stream){
  const float* q    = (const float*)d_in[0];
  const float* k    = (const float*)d_in[1];
  const float* v    = (const float*)d_in[2];
  const float* proj = (const float*)d_in[3];
  float* out = (float*)d_out;
  char* ws = (char*)d_ws;
  short* wproj_h = (short*)(ws);
  float* wctx    = (float*)(ws + 73728);
  float* wksump  = (float*)(ws + 18948096);          // 73728 + 256*288*64*4
  short* wct_h   = (short*)(ws + 19243008);          // + 256*288*4
  float* wksum   = (float*)(ws + 20422656);          // + 32*64*288*2

  const double LOG2E = 1.4426950408889634;
  const double ln_ratio = -0.5*log(266.0);
  float pscale = (float)(pow(64.0, -0.25) * LOG2E);
  float diagc  = (float)(0.0625 * LOG2E);
  float koff   = (float)((1e-4 + ln_ratio) * LOG2E);
  float qoff   = (float)(ln_ratio * LOG2E);
  float qeps   = (float)(1e-4 / sqrt(266.0));

  hipFuncSetAttribute((const void*)fa21_p1, hipFuncAttributeMaxDynamicSharedMemorySize, 122880);
  hipFuncSetAttribute((const void*)fa21_p2, hipFuncAttributeMaxDynamicSharedMemorySize, 87296);

  fa21_prep<<<72, 256, 0, stream>>>(proj, wproj_h, pscale);
  fa21_p1<<<256, 1024, 122880, stream>>>(k, v, wproj_h, wctx, wksump, koff, diagc);
  fa21_reduce<<<256, 256, 0, stream>>>(wctx, wksump, wct_h, wksum);
  fa21_p2<<<256, 1024, 87296, stream>>>(q, wproj_h, wct_h, wksum, out,
                                        qoff, qeps, diagc);
}